// Round 1
// baseline (6543.086 us; speedup 1.0000x reference)
//
#include <hip/hip_runtime.h>

#define HC 252
#define WC 252
#define CD 256
#define NHEADS 16

// ---------------- Kernel A: fused qkv (1x1 conv) + window attention ----------
// grid 2048 = (b:2, wy:32, wx:32), 256 threads. LDS ~133KB -> 1 block/CU.
__global__ __launch_bounds__(256) void attn_kernel(
    const float* __restrict__ x, const float* __restrict__ w_qkv,
    const float* __restrict__ bias_table, float* __restrict__ out)
{
    __shared__ float xs[256][68];   // [ci][pos], transposed window, pad 68 for b128
    __shared__ float wl[256][49];   // [ci][o], o<48 (q:0-15,k:16-31,v:32-47)
    __shared__ float qs[64][17], ks[64][17], vs[64][17];

    const int blk = blockIdx.x;
    const int wx = blk & 31, wy = (blk >> 5) & 31, b = blk >> 10;
    const int tid = threadIdx.x;

    // stage x window (reflect-padded 256x256 view), transposed into LDS
    for (int it = 0; it < 64; ++it) {
        int flat = tid + (it << 8);
        int ci = flat >> 6, pos = flat & 63;
        int r = pos >> 3, c = pos & 7;
        int h = wy * 8 + r; if (h >= HC) h = 2 * HC - 2 - h;
        int w = wx * 8 + c; if (w >= WC) w = 2 * WC - 2 - w;
        xs[ci][pos] = x[((b * CD + ci) * HC + h) * WC + w];
    }

    const int pg = tid & 15, j4 = tid >> 4;   // qkv-phase mapping
    const int i_ = tid >> 2, sub = tid & 3;   // attn-phase mapping
    const int r_ = i_ >> 3, c_ = i_ & 7;
    const int oh = wy * 8 + r_, ow = wx * 8 + c_;

    for (int head = 0; head < NHEADS; ++head) {
        __syncthreads();
        // stage this head's qkv weights: wl[ci][o], o = part*16+dd
        for (int it = 0; it < 48; ++it) {
            int part = it >> 4, dd = it & 15;
            wl[tid][it] = w_qkv[((part << 8) + (head << 4) + dd) * 256 + tid];
        }
        __syncthreads();

        // qkv compute: thread -> pos = pg*4+pp (4), o = j4*3+oo (3)
        float acc[3][4];
        #pragma unroll
        for (int oo = 0; oo < 3; ++oo)
            #pragma unroll
            for (int pp = 0; pp < 4; ++pp) acc[oo][pp] = 0.f;
        for (int ci = 0; ci < 256; ++ci) {
            const float4 xv = *(const float4*)&xs[ci][pg * 4];
            const float w0 = wl[ci][j4 * 3 + 0];
            const float w1 = wl[ci][j4 * 3 + 1];
            const float w2 = wl[ci][j4 * 3 + 2];
            acc[0][0] += w0 * xv.x; acc[0][1] += w0 * xv.y; acc[0][2] += w0 * xv.z; acc[0][3] += w0 * xv.w;
            acc[1][0] += w1 * xv.x; acc[1][1] += w1 * xv.y; acc[1][2] += w1 * xv.z; acc[1][3] += w1 * xv.w;
            acc[2][0] += w2 * xv.x; acc[2][1] += w2 * xv.y; acc[2][2] += w2 * xv.z; acc[2][3] += w2 * xv.w;
        }
        #pragma unroll
        for (int oo = 0; oo < 3; ++oo) {
            int o = j4 * 3 + oo;
            int part = o >> 4, dd = o & 15;
            float* dst = (part == 0) ? &qs[0][0] : (part == 1) ? &ks[0][0] : &vs[0][0];
            #pragma unroll
            for (int pp = 0; pp < 4; ++pp) {
                int pos = pg * 4 + pp;
                dst[pos * 17 + dd] = acc[oo][pp];
            }
        }
        __syncthreads();

        // attention: thread (i_, sub); owns j in [sub*16, sub*16+16)
        float qv[16];
        #pragma unroll
        for (int d = 0; d < 16; ++d) qv[d] = qs[i_][d];
        float pv[16];
        float mx = -1e30f;
        #pragma unroll
        for (int jj = 0; jj < 16; ++jj) {
            int j = sub * 16 + jj;
            float s = 0.f;
            #pragma unroll
            for (int d = 0; d < 16; ++d) s += qv[d] * ks[j][d];
            int dy = r_ - (j >> 3), dx = c_ - (j & 7);
            s = s * 0.25f + bias_table[((dy + 7) * 15 + (dx + 7)) * NHEADS + head];
            pv[jj] = s;
            mx = fmaxf(mx, s);
        }
        mx = fmaxf(mx, __shfl_xor(mx, 1));
        mx = fmaxf(mx, __shfl_xor(mx, 2));
        float sum = 0.f;
        #pragma unroll
        for (int jj = 0; jj < 16; ++jj) { pv[jj] = __expf(pv[jj] - mx); sum += pv[jj]; }
        sum += __shfl_xor(sum, 1);
        sum += __shfl_xor(sum, 2);
        const float inv = 1.0f / sum;
        float po[16];
        #pragma unroll
        for (int d = 0; d < 16; ++d) po[d] = 0.f;
        #pragma unroll
        for (int jj = 0; jj < 16; ++jj) {
            const float a = pv[jj] * inv;
            const int j = sub * 16 + jj;
            #pragma unroll
            for (int d = 0; d < 16; ++d) po[d] += a * vs[j][d];
        }
        #pragma unroll
        for (int d = 0; d < 16; ++d) {
            po[d] += __shfl_xor(po[d], 1);
            po[d] += __shfl_xor(po[d], 2);
        }
        if (oh < HC && ow < WC) {
            #pragma unroll
            for (int q2 = 0; q2 < 4; ++q2) {
                int dd = sub * 4 + q2;
                out[((b * CD + (head << 4) + dd) * HC + oh) * WC + ow] = po[dd];
            }
        }
    }
}

#define MAC16()                                                                 \
    {                                                                           \
        acc[0][0] += a.x * bb.x; acc[0][1] += a.x * bb.y;                       \
        acc[0][2] += a.x * bb.z; acc[0][3] += a.x * bb.w;                       \
        acc[1][0] += a.y * bb.x; acc[1][1] += a.y * bb.y;                       \
        acc[1][2] += a.y * bb.z; acc[1][3] += a.y * bb.w;                       \
        acc[2][0] += a.z * bb.x; acc[2][1] += a.z * bb.y;                       \
        acc[2][2] += a.z * bb.z; acc[2][3] += a.z * bb.w;                       \
        acc[3][0] += a.w * bb.x; acc[3][1] += a.w * bb.y;                       \
        acc[3][2] += a.w * bb.z; acc[3][3] += a.w * bb.w;                       \
    }

// ---------------- Kernel B: p = conv_h(out) + b_h + conv_v(out) + b_v --------
// Two fused K=2048 GEMMs. grid (wt:4, ct:4, b*252), 64co x 64w tile per block.
__global__ __launch_bounds__(256) void sepconv_kernel(
    const float* __restrict__ X, const float* __restrict__ w_h,
    const float* __restrict__ b_h, const float* __restrict__ w_v,
    const float* __restrict__ b_v, float* __restrict__ P)
{
    __shared__ float As[32][68];
    __shared__ float Bs[32][68];
    const int wt = blockIdx.x, ct = blockIdx.y;
    const int bh = blockIdx.z;
    const int h = bh % HC, b = bh / HC;
    const int co0 = ct * 64, w0 = wt * 64;
    const int tid = threadIdx.x, tx = tid & 15, ty = tid >> 4;

    float acc[4][4];
    #pragma unroll
    for (int mc = 0; mc < 4; ++mc) {
        float bias = b_h[co0 + ty * 4 + mc] + b_v[co0 + ty * 4 + mc];
        #pragma unroll
        for (int mw = 0; mw < 4; ++mw) acc[mc][mw] = bias;
    }

    const int sa_co = tid >> 5, sa_kk = tid & 31;
    const int sb_kk = tid >> 6, sb_wi = tid & 63;

    for (int phase = 0; phase < 2; ++phase) {
        const float* __restrict__ Wg = phase ? w_v : w_h;
        for (int kc = 0; kc < 64; ++kc) {
            const int kbase = kc << 5;
            __syncthreads();
            #pragma unroll
            for (int it = 0; it < 8; ++it) {
                int co_l = sa_co + it * 8;
                As[sa_kk][co_l] = Wg[(co0 + co_l) * 2048 + kbase + sa_kk];
            }
            #pragma unroll
            for (int it = 0; it < 8; ++it) {
                int kk = sb_kk + it * 4;
                int kg = kbase + kk;
                int ci = kg >> 3, t = kg & 7;
                float v = 0.f;
                if (phase == 0) {
                    int j = h + t - 3;                 // row tap (reflect+zero pad)
                    if (j >= 0 && j <= HC) {
                        int jr = (j == HC) ? (HC - 2) : j;
                        int wg = w0 + sb_wi; if (wg > WC - 1) wg = WC - 1;
                        v = X[((b * CD + ci) * HC + jr) * WC + wg];
                    }
                } else {
                    int j2 = w0 + sb_wi + t - 3;       // col tap
                    if (j2 >= 0 && j2 <= WC) {
                        int j2r = (j2 == WC) ? (WC - 2) : j2;
                        v = X[((b * CD + ci) * HC + h) * WC + j2r];
                    }
                }
                Bs[kk][sb_wi] = v;
            }
            __syncthreads();
            #pragma unroll
            for (int k = 0; k < 32; ++k) {
                const float4 a  = *(const float4*)&As[k][ty * 4];
                const float4 bb = *(const float4*)&Bs[k][tx * 4];
                MAC16();
            }
        }
    }
    #pragma unroll
    for (int mc = 0; mc < 4; ++mc) {
        int co = co0 + ty * 4 + mc;
        #pragma unroll
        for (int mw = 0; mw < 4; ++mw) {
            int w = w0 + tx * 4 + mw;
            if (w < WC) P[((b * CD + co) * HC + h) * WC + w] = acc[mc][mw];
        }
    }
}

// ---------------- Kernel C: depthwise 8x8 conv + BN --------------------------
__global__ __launch_bounds__(256) void dwbn_kernel(
    const float* __restrict__ P, const float* __restrict__ w_dw,
    const float* __restrict__ gamma, const float* __restrict__ beta,
    const float* __restrict__ mean, const float* __restrict__ var,
    float* __restrict__ Y)
{
    __shared__ float ps[15][42];
    __shared__ float wd[64];
    const int bw = blockIdx.x, bh = blockIdx.y, bz = blockIdx.z;
    const int b = bz >> 8, c = bz & 255;
    const int h0 = bh * 8, w0 = bw * 32;
    const int tid = threadIdx.x;
    if (tid < 64) wd[tid] = w_dw[c * 64 + tid];
    for (int it = 0; it < 3; ++it) {
        int flat = tid + it * 256;
        if (flat < 630) {
            int row = flat / 42, col = flat % 42;
            int j = h0 - 3 + row, wcol = w0 - 3 + col;
            float v = 0.f;
            if (j >= 0 && j <= HC && wcol >= 0 && wcol <= WC) {
                int jr = (j == HC) ? (HC - 2) : j;
                int wr = (wcol == WC) ? (WC - 2) : wcol;
                v = P[((b * CD + c) * HC + jr) * WC + wr];
            }
            ps[row][col] = v;
        }
    }
    __syncthreads();
    const int r = tid >> 5, cc = tid & 31;
    const int h = h0 + r, w = w0 + cc;
    if (h < HC && w < WC) {
        float s = 0.f;
        #pragma unroll
        for (int u = 0; u < 8; ++u)
            #pragma unroll
            for (int v2 = 0; v2 < 8; ++v2)
                s += wd[u * 8 + v2] * ps[r + u][cc + v2];
        const float inv = gamma[c] * rsqrtf(var[c] + 1e-5f);
        Y[((b * CD + c) * HC + h) * WC + w] = s * inv + (beta[c] - mean[c] * inv);
    }
}

// ---------------- Kernel D: pointwise 1x1 conv (K=256 GEMM) ------------------
__global__ __launch_bounds__(256) void pw_kernel(
    const float* __restrict__ Y, const float* __restrict__ w_pw,
    float* __restrict__ O)
{
    __shared__ float As[32][68];
    __shared__ float Bs[32][68];
    const int wt = blockIdx.x, ct = blockIdx.y, bh = blockIdx.z;
    const int h = bh % HC, b = bh / HC;
    const int co0 = ct * 64, w0 = wt * 64;
    const int tid = threadIdx.x, tx = tid & 15, ty = tid >> 4;
    float acc[4][4];
    #pragma unroll
    for (int mc = 0; mc < 4; ++mc)
        #pragma unroll
        for (int mw = 0; mw < 4; ++mw) acc[mc][mw] = 0.f;

    const int sa_co = tid >> 5, sa_kk = tid & 31;
    const int sb_kk = tid >> 6, sb_wi = tid & 63;

    for (int kc = 0; kc < 8; ++kc) {
        const int kbase = kc << 5;
        __syncthreads();
        #pragma unroll
        for (int it = 0; it < 8; ++it) {
            int co_l = sa_co + it * 8;
            As[sa_kk][co_l] = w_pw[(co0 + co_l) * 256 + kbase + sa_kk];
        }
        #pragma unroll
        for (int it = 0; it < 8; ++it) {
            int kk = sb_kk + it * 4;
            int ci = kbase + kk;
            int wg = w0 + sb_wi; if (wg > WC - 1) wg = WC - 1;
            Bs[kk][sb_wi] = Y[((b * CD + ci) * HC + h) * WC + wg];
        }
        __syncthreads();
        #pragma unroll
        for (int k = 0; k < 32; ++k) {
            const float4 a  = *(const float4*)&As[k][ty * 4];
            const float4 bb = *(const float4*)&Bs[k][tx * 4];
            MAC16();
        }
    }
    #pragma unroll
    for (int mc = 0; mc < 4; ++mc) {
        int co = co0 + ty * 4 + mc;
        #pragma unroll
        for (int mw = 0; mw < 4; ++mw) {
            int w = w0 + tx * 4 + mw;
            if (w < WC) O[((b * CD + co) * HC + h) * WC + w] = acc[mc][mw];
        }
    }
}

extern "C" void kernel_launch(void* const* d_in, const int* in_sizes, int n_in,
                              void* d_out, int out_size, void* d_ws, size_t ws_size,
                              hipStream_t stream)
{
    const float* x      = (const float*)d_in[0];
    const float* w_qkv  = (const float*)d_in[1];
    const float* bias_t = (const float*)d_in[2];
    const float* w_h    = (const float*)d_in[3];
    const float* b_h    = (const float*)d_in[4];
    const float* w_v    = (const float*)d_in[5];
    const float* b_v    = (const float*)d_in[6];
    const float* w_dw   = (const float*)d_in[7];
    const float* bn_g   = (const float*)d_in[8];
    const float* bn_b   = (const float*)d_in[9];
    const float* bn_m   = (const float*)d_in[10];
    const float* bn_v   = (const float*)d_in[11];
    const float* w_pw   = (const float*)d_in[12];
    float* out = (float*)d_out;
    float* wsA = (float*)d_ws;   // one (B,256,252,252) fp32 buffer: ~130 MB

    // attn-out -> ws ; p -> d_out ; y -> ws (overwrites dead attn-out) ;
    // final -> d_out (overwrites dead p)
    attn_kernel<<<2048, 256, 0, stream>>>(x, w_qkv, bias_t, wsA);
    sepconv_kernel<<<dim3(4, 4, 2 * HC), 256, 0, stream>>>(wsA, w_h, b_h, w_v, b_v, out);
    dwbn_kernel<<<dim3(8, 32, 2 * CD), 256, 0, stream>>>(out, w_dw, bn_g, bn_b, bn_m, bn_v, wsA);
    pw_kernel<<<dim3(4, 4, 2 * HC), 256, 0, stream>>>(wsA, w_pw, out);
}

// Round 2
// 2427.790 us; speedup vs baseline: 2.6951x; 2.6951x over previous
//
#include <hip/hip_runtime.h>
#include <hip/hip_bf16.h>

#define HC 252
#define WC 252
#define CD 256
#define NHEADS 16

// XP padded image: [b][ci][h 0..251][wp 0..263], wp = w_img + 4
#define XP_W 264
#define XP_HW (252*264)
#define XP_CHW (256*252*264)

typedef unsigned short u16;
typedef unsigned int u32;
typedef __attribute__((ext_vector_type(8))) short bf16x8;
typedef __attribute__((ext_vector_type(4))) float f32x4;
typedef __attribute__((ext_vector_type(4))) u32 u32x4;

// ---- workspace layout (bytes) ----
#define XP_BYTES (2u * (unsigned)XP_CHW * 2u)      // 68,124,672
#define ZP_OFF   XP_BYTES
#define ZP_BYTES 409600u                           // zero page (covers cil*XP_HW spread)
#define WT_OFF   (ZP_OFF + ZP_BYTES)
#define WT_ELEMS (2*128*4*128*8)                   // 1,048,576 bf16
#define WPW_OFF  (WT_OFF + (unsigned)WT_ELEMS*2u)
#define WPW_ELEMS (2*8*4*128*8)                    // 65,536 bf16

// ---------------- Kernel A: fused qkv (1x1 conv) + window attention ----------
// grid 2048 = (b:2, wy:32, wx:32), 256 threads. Writes bf16 into XP interior.
__global__ __launch_bounds__(256) void attn_kernel(
    const float* __restrict__ x, const float* __restrict__ w_qkv,
    const float* __restrict__ bias_table, __hip_bfloat16* __restrict__ xp)
{
    __shared__ float xs[256][68];
    __shared__ float wl[256][49];
    __shared__ float qs[64][17], ks[64][17], vs[64][17];

    const int blk = blockIdx.x;
    const int wx = blk & 31, wy = (blk >> 5) & 31, b = blk >> 10;
    const int tid = threadIdx.x;

    for (int it = 0; it < 64; ++it) {
        int flat = tid + (it << 8);
        int ci = flat >> 6, pos = flat & 63;
        int r = pos >> 3, c = pos & 7;
        int h = wy * 8 + r; if (h >= HC) h = 2 * HC - 2 - h;
        int w = wx * 8 + c; if (w >= WC) w = 2 * WC - 2 - w;
        xs[ci][pos] = x[((b * CD + ci) * HC + h) * WC + w];
    }

    const int pg = tid & 15, j4 = tid >> 4;
    const int i_ = tid >> 2, sub = tid & 3;
    const int r_ = i_ >> 3, c_ = i_ & 7;
    const int oh = wy * 8 + r_, ow = wx * 8 + c_;

    for (int head = 0; head < NHEADS; ++head) {
        __syncthreads();
        for (int it = 0; it < 48; ++it) {
            int part = it >> 4, dd = it & 15;
            wl[tid][it] = w_qkv[((part << 8) + (head << 4) + dd) * 256 + tid];
        }
        __syncthreads();

        float acc[3][4];
        #pragma unroll
        for (int oo = 0; oo < 3; ++oo)
            #pragma unroll
            for (int pp = 0; pp < 4; ++pp) acc[oo][pp] = 0.f;
        for (int ci = 0; ci < 256; ++ci) {
            const float4 xv = *(const float4*)&xs[ci][pg * 4];
            const float w0 = wl[ci][j4 * 3 + 0];
            const float w1 = wl[ci][j4 * 3 + 1];
            const float w2 = wl[ci][j4 * 3 + 2];
            acc[0][0] += w0 * xv.x; acc[0][1] += w0 * xv.y; acc[0][2] += w0 * xv.z; acc[0][3] += w0 * xv.w;
            acc[1][0] += w1 * xv.x; acc[1][1] += w1 * xv.y; acc[1][2] += w1 * xv.z; acc[1][3] += w1 * xv.w;
            acc[2][0] += w2 * xv.x; acc[2][1] += w2 * xv.y; acc[2][2] += w2 * xv.z; acc[2][3] += w2 * xv.w;
        }
        #pragma unroll
        for (int oo = 0; oo < 3; ++oo) {
            int o = j4 * 3 + oo;
            int part = o >> 4, dd = o & 15;
            float* dst = (part == 0) ? &qs[0][0] : (part == 1) ? &ks[0][0] : &vs[0][0];
            #pragma unroll
            for (int pp = 0; pp < 4; ++pp) {
                int pos = pg * 4 + pp;
                dst[pos * 17 + dd] = acc[oo][pp];
            }
        }
        __syncthreads();

        float qv[16];
        #pragma unroll
        for (int d = 0; d < 16; ++d) qv[d] = qs[i_][d];
        float pv[16];
        float mx = -1e30f;
        #pragma unroll
        for (int jj = 0; jj < 16; ++jj) {
            int j = sub * 16 + jj;
            float s = 0.f;
            #pragma unroll
            for (int d = 0; d < 16; ++d) s += qv[d] * ks[j][d];
            int dy = r_ - (j >> 3), dx = c_ - (j & 7);
            s = s * 0.25f + bias_table[((dy + 7) * 15 + (dx + 7)) * NHEADS + head];
            pv[jj] = s;
            mx = fmaxf(mx, s);
        }
        mx = fmaxf(mx, __shfl_xor(mx, 1));
        mx = fmaxf(mx, __shfl_xor(mx, 2));
        float sum = 0.f;
        #pragma unroll
        for (int jj = 0; jj < 16; ++jj) { pv[jj] = __expf(pv[jj] - mx); sum += pv[jj]; }
        sum += __shfl_xor(sum, 1);
        sum += __shfl_xor(sum, 2);
        const float inv = 1.0f / sum;
        float po[16];
        #pragma unroll
        for (int d = 0; d < 16; ++d) po[d] = 0.f;
        #pragma unroll
        for (int jj = 0; jj < 16; ++jj) {
            const float a = pv[jj] * inv;
            const int j = sub * 16 + jj;
            #pragma unroll
            for (int d = 0; d < 16; ++d) po[d] += a * vs[j][d];
        }
        #pragma unroll
        for (int d = 0; d < 16; ++d) {
            po[d] += __shfl_xor(po[d], 1);
            po[d] += __shfl_xor(po[d], 2);
        }
        if (oh < HC && ow < WC) {
            #pragma unroll
            for (int q2 = 0; q2 < 4; ++q2) {
                int dd = sub * 4 + q2;
                xp[((b * CD + (head << 4) + dd) * HC + oh) * XP_W + (ow + 4)] =
                    __float2bfloat16(po[dd]);
            }
        }
    }
}

// ---------------- weight prep: Wt (sepconv), Wp (pointwise), zero page -------
__global__ __launch_bounds__(256) void wprep_kernel(
    const float* __restrict__ wh, const float* __restrict__ wv,
    const float* __restrict__ wpw, u16* __restrict__ wsu)
{
    int i = blockIdx.x * 256 + threadIdx.x;
    u16* WT = wsu + WT_OFF / 2;
    u16* WP = wsu + WPW_OFF / 2;
    u16* ZP = wsu + ZP_OFF / 2;
    if (i < WT_ELEMS) {
        int j = i & 7, co = (i >> 3) & 127, kb = (i >> 10) & 3, s = (i >> 12) & 127, ct = i >> 19;
        int cog = ct * 128 + co;
        float v = (s < 64) ? wh[cog * 2048 + s * 32 + kb * 8 + j]
                           : wv[cog * 2048 + (s - 64) * 32 + kb * 8 + j];
        __hip_bfloat16 bv = __float2bfloat16(v);
        WT[i] = *(const u16*)&bv;
    } else if (i < WT_ELEMS + WPW_ELEMS) {
        int i2 = i - WT_ELEMS;
        int j = i2 & 7, co = (i2 >> 3) & 127, kb = (i2 >> 10) & 3, s = (i2 >> 12) & 7, ct = (i2 >> 15) & 1;
        float v = wpw[(ct * 128 + co) * 256 + s * 32 + kb * 8 + j];
        __hip_bfloat16 bv = __float2bfloat16(v);
        WP[i2] = *(const u16*)&bv;
    } else {
        int i3 = i - WT_ELEMS - WPW_ELEMS;
        if (i3 < (int)(ZP_BYTES / 2)) ZP[i3] = 0;
    }
}

// ---------------- halo fill for XP (after attn): wp 0..3, 256..263 -----------
__global__ __launch_bounds__(256) void halo_kernel(u16* __restrict__ xp)
{
    int i = blockIdx.x * 256 + threadIdx.x;
    if (i >= 129024 * 12) return;
    int row = i / 12, c = i % 12;
    int wp = (c < 4) ? c : 252 + c;       // 0..3 or 256..263
    u16 v = 0;
    if (wp == 256) v = xp[row * XP_W + 254];   // reflect: w=252 -> w=250
    xp[row * XP_W + wp] = v;
}

// ---------------- Kernel B: sepconv as bf16 MFMA, K=4096 (h:2048 + v:2048) ---
// grid (wt:2, ct:2, b*252). 128co x 128w tile, 4 waves, BK=32.
__global__ __launch_bounds__(256) void sepconv_mfma(
    const u16* __restrict__ xp, const u16* __restrict__ WT,
    const u16* __restrict__ ZP,
    const float* __restrict__ b_h, const float* __restrict__ b_v,
    float* __restrict__ P)
{
    __shared__ u16 As[4096];          // [kblk][co][8] linear, conflict-free
    __shared__ u16 Bs[128 * 40];      // [w][kk] padded rows (40 u16)

    const int wt = blockIdx.x, ct = blockIdx.y;
    const int h = blockIdx.z % HC, b = blockIdx.z / HC;
    const int w0 = wt * 128, co0 = ct * 128;
    const int tid = threadIdx.x;
    const int lane = tid & 63, wid = tid >> 6;
    const int wr = wid >> 1, wc = wid & 1;

    const int wl2 = (tid & 63) * 2;   // B-stage: w pair
    const int cil = tid >> 6;         // B-stage: local k-octet (ci within BK)

    // h-phase per-tap row pointers (block-uniform), ZP for invalid taps
    const u16* hrow[8];
    int hstep[8];
    #pragma unroll
    for (int t = 0; t < 8; ++t) {
        int j = h + t - 3;
        bool valid = (j >= 0 && j <= 252);
        int jr = (j == 252) ? 250 : j;
        hrow[t] = valid ? (xp + (size_t)b * XP_CHW + (size_t)jr * XP_W) : ZP;
        hstep[t] = valid ? 4 * XP_HW : 0;
    }
    const int hvoff = cil * XP_HW + w0 + wl2 + 4;  // u16 units
    const u16* vrow = xp + (size_t)b * XP_CHW + (size_t)h * XP_W;
    const int vvoff = cil * XP_HW + w0 + wl2;      // covers wp base..base+11

    const int bw0 = wl2 * 40 + cil * 8;            // Bs u16 offsets
    const int bw1 = bw0 + 40;

    const u16* wtp = WT + (size_t)(ct * 128) * 4096;

    f32x4 acc[4][4];
    #pragma unroll
    for (int m = 0; m < 4; ++m)
        #pragma unroll
        for (int n = 0; n < 4; ++n) acc[m][n] = (f32x4){0.f, 0.f, 0.f, 0.f};

    const int kb = lane >> 4;
    const int cq = lane & 15;

    for (int s = 0; s < 128; ++s) {
        // issue global loads for this step's tiles
        u32x4 a0 = *(const u32x4*)(wtp + (size_t)s * 4096 + tid * 8);
        u32x4 a1 = *(const u32x4*)(wtp + (size_t)s * 4096 + (tid + 256) * 8);
        u32 r[8];
        if (s < 64) {
            #pragma unroll
            for (int t = 0; t < 8; ++t)
                r[t] = *(const u32*)(hrow[t] + hvoff);
        } else {
            #pragma unroll
            for (int l = 0; l < 6; ++l)
                r[l] = *(const u32*)(vrow + vvoff + 2 * l);
        }
        __syncthreads();
        *(u32x4*)&As[tid * 8] = a0;
        *(u32x4*)&As[(tid + 256) * 8] = a1;
        union { bf16x8 v; u32 u[4]; } p0, p1;
        if (s < 64) {
            // per tap t: r[t] = (X[jt][w], X[jt][w+1]); split lo/hi halves
            #pragma unroll
            for (int q = 0; q < 4; ++q) {
                p0.u[q] = __builtin_amdgcn_perm(r[2 * q + 1], r[2 * q], 0x05040100u);
                p1.u[q] = __builtin_amdgcn_perm(r[2 * q + 1], r[2 * q], 0x07060302u);
            }
        } else {
            // halfword stream H[p]; w needs p=1..8, w+1 needs p=2..9
            #pragma unroll
            for (int q = 0; q < 4; ++q)
                p0.u[q] = __builtin_amdgcn_alignbit(r[q + 1], r[q], 16);
            p1.u[0] = r[1]; p1.u[1] = r[2]; p1.u[2] = r[3]; p1.u[3] = r[4];
        }
        *(bf16x8*)&Bs[bw0] = p0.v;
        *(bf16x8*)&Bs[bw1] = p1.v;
        if (s < 64) {
            #pragma unroll
            for (int t = 0; t < 8; ++t) hrow[t] += hstep[t];
        } else {
            vrow += 4 * XP_HW;
        }
        __syncthreads();

        bf16x8 af[4], bfr[4];
        #pragma unroll
        for (int m = 0; m < 4; ++m)
            af[m] = *(const bf16x8*)&As[kb * 1024 + (wr * 64 + m * 16 + cq) * 8];
        #pragma unroll
        for (int n = 0; n < 4; ++n) {
            int wcol = wc * 64 + n * 16 + cq;
            bfr[n] = *(const bf16x8*)&Bs[wcol * 40 + kb * 8];
        }
        #pragma unroll
        for (int m = 0; m < 4; ++m)
            #pragma unroll
            for (int n = 0; n < 4; ++n)
                acc[m][n] = __builtin_amdgcn_mfma_f32_16x16x32_bf16(af[m], bfr[n], acc[m][n], 0, 0, 0);
    }

    // epilogue: bias + store fp32 P
    const int rq = lane >> 4, cc = lane & 15;
    #pragma unroll
    for (int m = 0; m < 4; ++m) {
        int cgb = co0 + wr * 64 + m * 16 + rq * 4;
        float bias[4];
        #pragma unroll
        for (int rr = 0; rr < 4; ++rr) bias[rr] = b_h[cgb + rr] + b_v[cgb + rr];
        #pragma unroll
        for (int n = 0; n < 4; ++n) {
            int wg = w0 + wc * 64 + n * 16 + cc;
            if (wg < WC) {
                #pragma unroll
                for (int rr = 0; rr < 4; ++rr)
                    P[((size_t)(b * CD + cgb + rr) * HC + h) * WC + wg] = acc[m][n][rr] + bias[rr];
            }
        }
    }
}

// ---------------- Kernel C: depthwise 8x8 conv + BN -> bf16 Y ----------------
__global__ __launch_bounds__(256) void dwbn_kernel(
    const float* __restrict__ P, const float* __restrict__ w_dw,
    const float* __restrict__ gamma, const float* __restrict__ beta,
    const float* __restrict__ mean, const float* __restrict__ var,
    __hip_bfloat16* __restrict__ Yb)
{
    __shared__ float ps[15][42];
    __shared__ float wd[64];
    const int bw = blockIdx.x, bh = blockIdx.y, bz = blockIdx.z;
    const int b = bz >> 8, c = bz & 255;
    const int h0 = bh * 8, w0 = bw * 32;
    const int tid = threadIdx.x;
    if (tid < 64) wd[tid] = w_dw[c * 64 + tid];
    for (int it = 0; it < 3; ++it) {
        int flat = tid + it * 256;
        if (flat < 630) {
            int row = flat / 42, col = flat % 42;
            int j = h0 - 3 + row, wcol = w0 - 3 + col;
            float v = 0.f;
            if (j >= 0 && j <= HC && wcol >= 0 && wcol <= WC) {
                int jr = (j == HC) ? (HC - 2) : j;
                int wr2 = (wcol == WC) ? (WC - 2) : wcol;
                v = P[((b * CD + c) * HC + jr) * WC + wr2];
            }
            ps[row][col] = v;
        }
    }
    __syncthreads();
    const int r = tid >> 5, cc = tid & 31;
    const int h = h0 + r, w = w0 + cc;
    if (h < HC && w < WC) {
        float s = 0.f;
        #pragma unroll
        for (int u = 0; u < 8; ++u)
            #pragma unroll
            for (int v2 = 0; v2 < 8; ++v2)
                s += wd[u * 8 + v2] * ps[r + u][cc + v2];
        const float inv = gamma[c] * rsqrtf(var[c] + 1e-5f);
        Yb[((b * CD + c) * HC + h) * WC + w] = __float2bfloat16(s * inv + (beta[c] - mean[c] * inv));
    }
}

// ---------------- Kernel D: pointwise 1x1 conv, bf16 MFMA, K=256 -------------
__global__ __launch_bounds__(256) void pw_mfma(
    const u16* __restrict__ Y, const u16* __restrict__ WP,
    float* __restrict__ O)
{
    __shared__ u16 As[4096];
    __shared__ u16 Bs[128 * 40];

    const int wt = blockIdx.x, ct = blockIdx.y;
    const int h = blockIdx.z % HC, b = blockIdx.z / HC;
    const int w0 = wt * 128, co0 = ct * 128;
    const int tid = threadIdx.x;
    const int lane = tid & 63, wid = tid >> 6;
    const int wr = wid >> 1, wc = wid & 1;

    const int wl2 = (tid & 63) * 2;
    const int grp = tid >> 6;
    const int bw0 = wl2 * 40 + grp * 8;
    const int bw1 = bw0 + 40;

    const u16* yb = Y + ((size_t)(b * CD + grp * 8) * HC + h) * WC + (w0 + wl2);
    const u16* wpp = WP + (size_t)ct * 8 * 4096;

    f32x4 acc[4][4];
    #pragma unroll
    for (int m = 0; m < 4; ++m)
        #pragma unroll
        for (int n = 0; n < 4; ++n) acc[m][n] = (f32x4){0.f, 0.f, 0.f, 0.f};

    const int kb = lane >> 4;
    const int cq = lane & 15;

    for (int s = 0; s < 8; ++s) {
        u32x4 a0 = *(const u32x4*)(wpp + (size_t)s * 4096 + tid * 8);
        u32x4 a1 = *(const u32x4*)(wpp + (size_t)s * 4096 + (tid + 256) * 8);
        u32 r[8];
        #pragma unroll
        for (int j = 0; j < 8; ++j)
            r[j] = *(const u32*)(yb + (size_t)j * (HC * WC));
        yb += (size_t)32 * HC * WC;
        __syncthreads();
        *(u32x4*)&As[tid * 8] = a0;
        *(u32x4*)&As[(tid + 256) * 8] = a1;
        union { bf16x8 v; u32 u[4]; } p0, p1;
        #pragma unroll
        for (int q = 0; q < 4; ++q) {
            p0.u[q] = __builtin_amdgcn_perm(r[2 * q + 1], r[2 * q], 0x05040100u);
            p1.u[q] = __builtin_amdgcn_perm(r[2 * q + 1], r[2 * q], 0x07060302u);
        }
        *(bf16x8*)&Bs[bw0] = p0.v;
        *(bf16x8*)&Bs[bw1] = p1.v;
        __syncthreads();

        bf16x8 af[4], bfr[4];
        #pragma unroll
        for (int m = 0; m < 4; ++m)
            af[m] = *(const bf16x8*)&As[kb * 1024 + (wr * 64 + m * 16 + cq) * 8];
        #pragma unroll
        for (int n = 0; n < 4; ++n) {
            int wcol = wc * 64 + n * 16 + cq;
            bfr[n] = *(const bf16x8*)&Bs[wcol * 40 + kb * 8];
        }
        #pragma unroll
        for (int m = 0; m < 4; ++m)
            #pragma unroll
            for (int n = 0; n < 4; ++n)
                acc[m][n] = __builtin_amdgcn_mfma_f32_16x16x32_bf16(af[m], bfr[n], acc[m][n], 0, 0, 0);
    }

    const int rq = lane >> 4;
    #pragma unroll
    for (int m = 0; m < 4; ++m) {
        int cgb = co0 + wr * 64 + m * 16 + rq * 4;
        #pragma unroll
        for (int n = 0; n < 4; ++n) {
            int wg = w0 + wc * 64 + n * 16 + cq;
            if (wg < WC) {
                #pragma unroll
                for (int rr = 0; rr < 4; ++rr)
                    O[((size_t)(b * CD + cgb + rr) * HC + h) * WC + wg] = acc[m][n][rr];
            }
        }
    }
}

extern "C" void kernel_launch(void* const* d_in, const int* in_sizes, int n_in,
                              void* d_out, int out_size, void* d_ws, size_t ws_size,
                              hipStream_t stream)
{
    const float* x      = (const float*)d_in[0];
    const float* w_qkv  = (const float*)d_in[1];
    const float* bias_t = (const float*)d_in[2];
    const float* w_h    = (const float*)d_in[3];
    const float* b_h    = (const float*)d_in[4];
    const float* w_v    = (const float*)d_in[5];
    const float* b_v    = (const float*)d_in[6];
    const float* w_dw   = (const float*)d_in[7];
    const float* bn_g   = (const float*)d_in[8];
    const float* bn_b   = (const float*)d_in[9];
    const float* bn_m   = (const float*)d_in[10];
    const float* bn_v   = (const float*)d_in[11];
    const float* w_pw   = (const float*)d_in[12];
    float* out = (float*)d_out;

    u16* wsu = (u16*)d_ws;
    const u16* XPu = wsu;
    const u16* ZPu = wsu + ZP_OFF / 2;
    const u16* WTu = wsu + WT_OFF / 2;
    const u16* WPu = wsu + WPW_OFF / 2;

    // attn -> XP(bf16, ws) ; prep weights ; fill XP halos ;
    // sepconv(MFMA) -> P(fp32, d_out) ; dwbn: P -> Y(bf16, ws@0, XP dead) ;
    // pw(MFMA): Y -> d_out (overwrites dead P)
    attn_kernel<<<2048, 256, 0, stream>>>(x, w_qkv, bias_t, (__hip_bfloat16*)d_ws);
    wprep_kernel<<<5152, 256, 0, stream>>>(w_h, w_v, w_pw, wsu);
    halo_kernel<<<6048, 256, 0, stream>>>(wsu);
    sepconv_mfma<<<dim3(2, 2, 2 * HC), 256, 0, stream>>>(XPu, WTu, ZPu, b_h, b_v, out);
    dwbn_kernel<<<dim3(8, 32, 512), 256, 0, stream>>>(out, w_dw, bn_g, bn_b, bn_m, bn_v,
                                                      (__hip_bfloat16*)d_ws);
    pw_mfma<<<dim3(2, 2, 2 * HC), 256, 0, stream>>>(wsu, WPu, out);
}

// Round 3
// 919.694 us; speedup vs baseline: 7.1144x; 2.6398x over previous
//
#include <hip/hip_runtime.h>
#include <hip/hip_bf16.h>

#define HC 252
#define WC 252
#define CD 256
#define NHEADS 16

// XP padded image: [b][ci][h 0..251][wp 0..263], wp = w_img + 4
#define XP_W 264
#define XP_HW (252*264)
#define XP_CHW (256*252*264)

typedef unsigned short u16;
typedef unsigned int u32;
typedef __attribute__((ext_vector_type(8))) short bf16x8;
typedef __attribute__((ext_vector_type(4))) float f32x4;
typedef __attribute__((ext_vector_type(4))) u32 u32x4;
typedef __attribute__((ext_vector_type(2))) u32 u32x2;

// ---- workspace layout (bytes) ----
#define XP_BYTES (2u * (unsigned)XP_CHW * 2u)      // 68,124,672
#define ZP_OFF   XP_BYTES
#define ZP_BYTES 409600u
#define WT_OFF   (ZP_OFF + ZP_BYTES)
#define WT_ELEMS (2*128*4*128*8)                   // 1,048,576 bf16
#define WPW_OFF  (WT_OFF + (unsigned)WT_ELEMS*2u)
#define WPW_ELEMS (2*8*4*128*8)                    // 65,536 bf16
#define WQ_OFF   (WPW_OFF + (unsigned)WPW_ELEMS*2u)
#define WQ_ELEMS (768*256)                         // 196,608 bf16
#define BIAS_OFF (WQ_OFF + (unsigned)WQ_ELEMS*2u)
#define BIAS_ELEMS (16*4*4*64*4)                   // 65,536 f32

__device__ __forceinline__ u16 bfu(float f) {
    __hip_bfloat16 h = __float2bfloat16(f);
    return *(reinterpret_cast<u16*>(&h));
}
__device__ __forceinline__ u32 pack2(float a, float b) {
    return (u32)bfu(a) | ((u32)bfu(b) << 16);
}

// ---------------- Kernel A: fused qkv + window attention (MFMA) --------------
// grid 2048 = (b:2, wy:32, wx:32), 512 threads (8 waves, 2 heads/wave).
__global__ __launch_bounds__(512, 2) void attn_mfma(
    const float* __restrict__ x, const u16* __restrict__ WQ,
    const float* __restrict__ BIASF, u16* __restrict__ xp)
{
    // LDS map (128KB total):
    //  [0,32768)       : Xwin[pos][ci] bf16, swz byte = pos*512 + ((ci*2)^((pos&7)<<4))
    //                    (reused after qkv as per-wave P-half buffers, 4KB each)
    //  [32768,131072)  : per wave 12288B: Q[2][64][16] | K[2][64][16] | V[2][8][16][8]
    __shared__ __align__(16) char smem[131072];

    const int blk = blockIdx.x;
    const int wx = blk & 31, wy = (blk >> 5) & 31, b = blk >> 10;
    const int tid = threadIdx.x;
    const int lane = tid & 63, wid = tid >> 6;
    const int g = lane >> 4, li = lane & 15;

    // ---- stage Xwin (fp32 x -> bf16 LDS, transposed, reflect-padded) ----
    {
        int ci = tid >> 1;
        int rbase = (tid & 1) * 4;
        const float* srcc = x + (size_t)(b * 256 + ci) * (HC * WC);
        #pragma unroll
        for (int rr = 0; rr < 4; ++rr) {
            int r = rbase + rr;
            int h = wy * 8 + r; if (h >= HC) h = 2 * HC - 2 - h;
            const float* src = srcc + h * WC;
            float v[8];
            if (wx == 31) {
                #pragma unroll
                for (int c = 0; c < 8; ++c) {
                    int w = 248 + c; if (w >= WC) w = 2 * WC - 2 - w;
                    v[c] = src[w];
                }
            } else {
                float4 f0 = *(const float4*)(src + wx * 8);
                float4 f1 = *(const float4*)(src + wx * 8 + 4);
                v[0]=f0.x; v[1]=f0.y; v[2]=f0.z; v[3]=f0.w;
                v[4]=f1.x; v[5]=f1.y; v[6]=f1.z; v[7]=f1.w;
            }
            #pragma unroll
            for (int c = 0; c < 8; ++c) {
                int pos = r * 8 + c;
                int byte = pos * 512 + ((ci * 2) ^ ((pos & 7) << 4));
                *(u16*)(smem + byte) = bfu(v[c]);
            }
        }
    }
    __syncthreads();

    const int QKVB = 32768 + wid * 12288;

    // ---- qkv GEMM: this wave's 2 heads (rows 32w..32w+31 of q/k/v parts) ----
    f32x4 acc[6][4];
    #pragma unroll
    for (int m = 0; m < 6; ++m)
        #pragma unroll
        for (int nf = 0; nf < 4; ++nf) acc[m][nf] = (f32x4){0.f,0.f,0.f,0.f};

    for (int ks = 0; ks < 8; ++ks) {
        bf16x8 bx[4];
        #pragma unroll
        for (int nf = 0; nf < 4; ++nf) {
            int pos = 16 * nf + li;
            int byte = pos * 512 + ((ks * 64 + 16 * g) ^ ((pos & 7) << 4));
            bx[nf] = *(const bf16x8*)(smem + byte);
        }
        #pragma unroll
        for (int m = 0; m < 6; ++m) {
            int p = m >> 1, hh2 = m & 1;
            int o = p * 256 + 32 * wid + 16 * hh2 + li;
            bf16x8 aw = *(const bf16x8*)(WQ + o * 256 + ks * 32 + 8 * g);
            #pragma unroll
            for (int nf = 0; nf < 4; ++nf)
                acc[m][nf] = __builtin_amdgcn_mfma_f32_16x16x32_bf16(aw, bx[nf], acc[m][nf], 0, 0, 0);
        }
    }
    __syncthreads();   // Xwin dead; its region becomes per-wave P buffers

    // ---- epilogue: Q/K -> [hh][pos][d] (swz), V -> [hh][q][d][8pos] ----
    #pragma unroll
    for (int m = 0; m < 6; ++m) {
        int p = m >> 1, hh2 = m & 1;
        if (p < 2) {
            char* base = smem + QKVB + p * 4096 + hh2 * 2048;
            #pragma unroll
            for (int nf = 0; nf < 4; ++nf) {
                int pos = 16 * nf + li;
                u32 lo = pack2(acc[m][nf][0], acc[m][nf][1]);
                u32 hi = pack2(acc[m][nf][2], acc[m][nf][3]);
                int byte = pos * 32 + ((8 * g) ^ (((pos >> 2) & 1) << 4));
                *(u32x2*)(base + byte) = (u32x2){lo, hi};
            }
        } else {
            char* base = smem + QKVB + 8192 + hh2 * 2048;
            #pragma unroll
            for (int nf = 0; nf < 4; ++nf) {
                int pos = 16 * nf + li;
                #pragma unroll
                for (int r = 0; r < 4; ++r) {
                    int d = 4 * g + r;
                    int byte = (pos >> 3) * 256 + d * 16 + (pos & 7) * 2;
                    *(u16*)(base + byte) = bfu(acc[m][nf][r]);
                }
            }
        }
    }

    const bf16x8 zf = {0,0,0,0,0,0,0,0};

    // ---- attention: 2 heads sequentially per wave ----
    for (int hh2 = 0; hh2 < 2; ++hh2) {
        const int head = 2 * wid + hh2;
        const char* Qb = smem + QKVB + hh2 * 2048;
        const char* Kb = smem + QKVB + 4096 + hh2 * 2048;
        const char* Vb = smem + QKVB + 8192 + hh2 * 2048;
        char* Pb = smem + wid * 4096;                 // in dead Xwin region

        // QK^T (k=0..15 real, 16..31 zero)
        f32x4 s[4][4];
        #pragma unroll
        for (int mf = 0; mf < 4; ++mf)
            #pragma unroll
            for (int nf = 0; nf < 4; ++nf) s[mf][nf] = (f32x4){0.f,0.f,0.f,0.f};
        bf16x8 bk[4];
        #pragma unroll
        for (int nf = 0; nf < 4; ++nf) {
            int pos = 16 * nf + li;
            bk[nf] = (g < 2) ? *(const bf16x8*)(Kb + pos * 32 + ((16 * g) ^ (((pos >> 2) & 1) << 4))) : zf;
        }
        #pragma unroll
        for (int mf = 0; mf < 4; ++mf) {
            int pos = 16 * mf + li;
            bf16x8 aq = (g < 2) ? *(const bf16x8*)(Qb + pos * 32 + ((16 * g) ^ (((pos >> 2) & 1) << 4))) : zf;
            #pragma unroll
            for (int nf = 0; nf < 4; ++nf)
                s[mf][nf] = __builtin_amdgcn_mfma_f32_16x16x32_bf16(aq, bk[nf], s[mf][nf], 0, 0, 0);
        }

        // bias + exp + row sums (no max-sub: scores bounded small)
        f32x4 e[4][4];
        f32x4 rs[4];
        #pragma unroll
        for (int mf = 0; mf < 4; ++mf) rs[mf] = (f32x4){0.f,0.f,0.f,0.f};
        #pragma unroll
        for (int mf = 0; mf < 4; ++mf)
            #pragma unroll
            for (int nf = 0; nf < 4; ++nf) {
                f32x4 b4 = *(const f32x4*)(BIASF + (((head * 4 + mf) * 4 + nf) * 64 + lane) * 4);
                #pragma unroll
                for (int r = 0; r < 4; ++r) {
                    float ev = __expf(s[mf][nf][r] * 0.25f + b4[r]);
                    e[mf][nf][r] = ev;
                    rs[mf][r] += ev;
                }
            }
        #pragma unroll
        for (int mf = 0; mf < 4; ++mf)
            #pragma unroll
            for (int r = 0; r < 4; ++r) {
                float t = rs[mf][r];
                t += __shfl_xor(t, 1); t += __shfl_xor(t, 2);
                t += __shfl_xor(t, 4); t += __shfl_xor(t, 8);
                rs[mf][r] = t;
            }

        // PV in two j-halves through the 4KB P buffer
        f32x4 o[4];
        #pragma unroll
        for (int mf = 0; mf < 4; ++mf) o[mf] = (f32x4){0.f,0.f,0.f,0.f};
        const bool even = !(lane & 1);
        #pragma unroll
        for (int hf = 0; hf < 2; ++hf) {
            #pragma unroll
            for (int mf = 0; mf < 4; ++mf)
                #pragma unroll
                for (int nfl = 0; nfl < 2; ++nfl) {
                    f32x4 ee = e[mf][2 * hf + nfl];
                    float p0 = __shfl_xor(ee[0], 1), p1 = __shfl_xor(ee[1], 1);
                    float p2 = __shfl_xor(ee[2], 1), p3 = __shfl_xor(ee[3], 1);
                    int jl = 16 * nfl + (li & ~1);
                    u32 w0, w1; int r0;
                    if (even) { w0 = pack2(ee[0], p0); w1 = pack2(ee[1], p1); r0 = 0; }
                    else      { w0 = pack2(p2, ee[2]); w1 = pack2(p3, ee[3]); r0 = 2; }
                    int i0 = 16 * mf + 4 * g + r0, i1 = i0 + 1;
                    *(u32*)(Pb + i0 * 64 + ((2 * jl) ^ ((i0 & 3) << 4))) = w0;
                    *(u32*)(Pb + i1 * 64 + ((2 * jl) ^ ((i1 & 3) << 4))) = w1;
                }
            bf16x8 bv = *(const bf16x8*)(Vb + (4 * hf + g) * 256 + li * 16);
            #pragma unroll
            for (int mf = 0; mf < 4; ++mf) {
                int i = 16 * mf + li;
                bf16x8 ap = *(const bf16x8*)(Pb + i * 64 + ((16 * g) ^ ((i & 3) << 4)));
                o[mf] = __builtin_amdgcn_mfma_f32_16x16x32_bf16(ap, bv, o[mf], 0, 0, 0);
            }
        }

        // scale by 1/rowsum (lane-aligned) and store 4 bf16 (8B) into XP interior
        #pragma unroll
        for (int mf = 0; mf < 4; ++mf) {
            int h = wy * 8 + 2 * mf + (g >> 1);
            int wbase = wx * 8 + 4 * (g & 1);
            if (h < HC && wbase < WC) {
                float v0 = o[mf][0] / rs[mf][0], v1 = o[mf][1] / rs[mf][1];
                float v2 = o[mf][2] / rs[mf][2], v3 = o[mf][3] / rs[mf][3];
                size_t idx = ((size_t)(b * 256 + head * 16 + li) * HC + h) * XP_W + wbase + 4;
                *(u32x2*)(xp + idx) = (u32x2){pack2(v0, v1), pack2(v2, v3)};
            }
        }
    }
}

// ---------------- weight prep: WT, WPW, ZP, WQ(bf16), BIASF ------------------
__global__ __launch_bounds__(256) void wprep_kernel(
    const float* __restrict__ wh, const float* __restrict__ wv,
    const float* __restrict__ wpw, const float* __restrict__ wqkv,
    const float* __restrict__ btab, u16* __restrict__ wsu)
{
    int i = blockIdx.x * 256 + threadIdx.x;
    u16* WT = wsu + WT_OFF / 2;
    u16* WP = wsu + WPW_OFF / 2;
    u16* ZP = wsu + ZP_OFF / 2;
    u16* WQp = wsu + WQ_OFF / 2;
    float* BF = (float*)(wsu + BIAS_OFF / 2);
    if (i < WT_ELEMS) {
        int j = i & 7, co = (i >> 3) & 127, kb = (i >> 10) & 3, s = (i >> 12) & 127, ct = i >> 19;
        int cog = ct * 128 + co;
        float v = (s < 64) ? wh[cog * 2048 + s * 32 + kb * 8 + j]
                           : wv[cog * 2048 + (s - 64) * 32 + kb * 8 + j];
        WT[i] = bfu(v);
    } else if (i < WT_ELEMS + WPW_ELEMS) {
        int i2 = i - WT_ELEMS;
        int j = i2 & 7, co = (i2 >> 3) & 127, kb = (i2 >> 10) & 3, s = (i2 >> 12) & 7, ct = (i2 >> 15) & 1;
        WP[i2] = bfu(wpw[(ct * 128 + co) * 256 + s * 32 + kb * 8 + j]);
    } else if (i < WT_ELEMS + WPW_ELEMS + (int)(ZP_BYTES / 2)) {
        ZP[i - WT_ELEMS - WPW_ELEMS] = 0;
    } else if (i < WT_ELEMS + WPW_ELEMS + (int)(ZP_BYTES / 2) + WQ_ELEMS) {
        int i4 = i - WT_ELEMS - WPW_ELEMS - (int)(ZP_BYTES / 2);
        WQp[i4] = bfu(wqkv[i4]);
    } else {
        int i5 = i - WT_ELEMS - WPW_ELEMS - (int)(ZP_BYTES / 2) - WQ_ELEMS;
        if (i5 < 16384) {
            int lane = i5 & 63, nf = (i5 >> 6) & 3, mf = (i5 >> 8) & 3, head = i5 >> 10;
            int gg = lane >> 4, ll = lane & 15;
            #pragma unroll
            for (int r = 0; r < 4; ++r) {
                int row = 16 * mf + 4 * gg + r;
                int col = 16 * nf + ll;
                int dy = (row >> 3) - (col >> 3) + 7;
                int dx = (row & 7) - (col & 7) + 7;
                BF[i5 * 4 + r] = btab[(dy * 15 + dx) * NHEADS + head];
            }
        }
    }
}

// ---------------- halo fill for XP: wp 0..3, 256..263 ------------------------
__global__ __launch_bounds__(256) void halo_kernel(u16* __restrict__ xp)
{
    int i = blockIdx.x * 256 + threadIdx.x;
    if (i >= 129024 * 12) return;
    int row = i / 12, c = i % 12;
    int wp = (c < 4) ? c : 252 + c;
    u16 v = 0;
    if (wp == 256) v = xp[row * XP_W + 254];
    xp[row * XP_W + wp] = v;
}

#define MAC16() /* unused in MFMA path */

// ---------------- Kernel B: sepconv as bf16 MFMA, K=4096 ---------------------
__global__ __launch_bounds__(256) void sepconv_mfma(
    const u16* __restrict__ xp, const u16* __restrict__ WT,
    const u16* __restrict__ ZP,
    const float* __restrict__ b_h, const float* __restrict__ b_v,
    float* __restrict__ P)
{
    __shared__ u16 As[4096];
    __shared__ u16 Bs[128 * 40];

    const int wt = blockIdx.x, ct = blockIdx.y;
    const int h = blockIdx.z % HC, b = blockIdx.z / HC;
    const int w0 = wt * 128, co0 = ct * 128;
    const int tid = threadIdx.x;
    const int lane = tid & 63, wid = tid >> 6;
    const int wr = wid >> 1, wc = wid & 1;

    const int wl2 = (tid & 63) * 2;
    const int cil = tid >> 6;

    const u16* hrow[8];
    int hstep[8];
    #pragma unroll
    for (int t = 0; t < 8; ++t) {
        int j = h + t - 3;
        bool valid = (j >= 0 && j <= 252);
        int jr = (j == 252) ? 250 : j;
        hrow[t] = valid ? (xp + (size_t)b * XP_CHW + (size_t)jr * XP_W) : ZP;
        hstep[t] = valid ? 4 * XP_HW : 0;
    }
    const int hvoff = cil * XP_HW + w0 + wl2 + 4;
    const u16* vrow = xp + (size_t)b * XP_CHW + (size_t)h * XP_W;
    const int vvoff = cil * XP_HW + w0 + wl2;

    const int bw0 = wl2 * 40 + cil * 8;
    const int bw1 = bw0 + 40;

    const u16* wtp = WT + (size_t)(ct * 128) * 4096;

    f32x4 acc[4][4];
    #pragma unroll
    for (int m = 0; m < 4; ++m)
        #pragma unroll
        for (int n = 0; n < 4; ++n) acc[m][n] = (f32x4){0.f, 0.f, 0.f, 0.f};

    const int kb = lane >> 4;
    const int cq = lane & 15;

    for (int s = 0; s < 128; ++s) {
        u32x4 a0 = *(const u32x4*)(wtp + (size_t)s * 4096 + tid * 8);
        u32x4 a1 = *(const u32x4*)(wtp + (size_t)s * 4096 + (tid + 256) * 8);
        u32 r[8];
        if (s < 64) {
            #pragma unroll
            for (int t = 0; t < 8; ++t)
                r[t] = *(const u32*)(hrow[t] + hvoff);
        } else {
            #pragma unroll
            for (int l = 0; l < 6; ++l)
                r[l] = *(const u32*)(vrow + vvoff + 2 * l);
        }
        __syncthreads();
        *(u32x4*)&As[tid * 8] = a0;
        *(u32x4*)&As[(tid + 256) * 8] = a1;
        union { bf16x8 v; u32 u[4]; } p0, p1;
        if (s < 64) {
            #pragma unroll
            for (int q = 0; q < 4; ++q) {
                p0.u[q] = __builtin_amdgcn_perm(r[2 * q + 1], r[2 * q], 0x05040100u);
                p1.u[q] = __builtin_amdgcn_perm(r[2 * q + 1], r[2 * q], 0x07060302u);
            }
        } else {
            #pragma unroll
            for (int q = 0; q < 4; ++q)
                p0.u[q] = __builtin_amdgcn_alignbit(r[q + 1], r[q], 16);
            p1.u[0] = r[1]; p1.u[1] = r[2]; p1.u[2] = r[3]; p1.u[3] = r[4];
        }
        *(bf16x8*)&Bs[bw0] = p0.v;
        *(bf16x8*)&Bs[bw1] = p1.v;
        if (s < 64) {
            #pragma unroll
            for (int t = 0; t < 8; ++t) hrow[t] += hstep[t];
        } else {
            vrow += 4 * XP_HW;
        }
        __syncthreads();

        bf16x8 af[4], bfr[4];
        #pragma unroll
        for (int m = 0; m < 4; ++m)
            af[m] = *(const bf16x8*)&As[kb * 1024 + (wr * 64 + m * 16 + cq) * 8];
        #pragma unroll
        for (int n = 0; n < 4; ++n) {
            int wcol = wc * 64 + n * 16 + cq;
            bfr[n] = *(const bf16x8*)&Bs[wcol * 40 + kb * 8];
        }
        #pragma unroll
        for (int m = 0; m < 4; ++m)
            #pragma unroll
            for (int n = 0; n < 4; ++n)
                acc[m][n] = __builtin_amdgcn_mfma_f32_16x16x32_bf16(af[m], bfr[n], acc[m][n], 0, 0, 0);
    }

    const int rq = lane >> 4, cc = lane & 15;
    #pragma unroll
    for (int m = 0; m < 4; ++m) {
        int cgb = co0 + wr * 64 + m * 16 + rq * 4;
        float bias[4];
        #pragma unroll
        for (int rr = 0; rr < 4; ++rr) bias[rr] = b_h[cgb + rr] + b_v[cgb + rr];
        #pragma unroll
        for (int n = 0; n < 4; ++n) {
            int wg = w0 + wc * 64 + n * 16 + cc;
            if (wg < WC) {
                #pragma unroll
                for (int rr = 0; rr < 4; ++rr)
                    P[((size_t)(b * CD + cgb + rr) * HC + h) * WC + wg] = acc[m][n][rr] + bias[rr];
            }
        }
    }
}

// ---------------- Kernel C: depthwise 8x8 conv + BN -> bf16 Y ----------------
__global__ __launch_bounds__(256) void dwbn_kernel(
    const float* __restrict__ P, const float* __restrict__ w_dw,
    const float* __restrict__ gamma, const float* __restrict__ beta,
    const float* __restrict__ mean, const float* __restrict__ var,
    __hip_bfloat16* __restrict__ Yb)
{
    __shared__ float ps[15][42];
    __shared__ float wd[64];
    const int bw = blockIdx.x, bh = blockIdx.y, bz = blockIdx.z;
    const int b = bz >> 8, c = bz & 255;
    const int h0 = bh * 8, w0 = bw * 32;
    const int tid = threadIdx.x;
    if (tid < 64) wd[tid] = w_dw[c * 64 + tid];
    for (int it = 0; it < 3; ++it) {
        int flat = tid + it * 256;
        if (flat < 630) {
            int row = flat / 42, col = flat % 42;
            int j = h0 - 3 + row, wcol = w0 - 3 + col;
            float v = 0.f;
            if (j >= 0 && j <= HC && wcol >= 0 && wcol <= WC) {
                int jr = (j == HC) ? (HC - 2) : j;
                int wr2 = (wcol == WC) ? (WC - 2) : wcol;
                v = P[((b * CD + c) * HC + jr) * WC + wr2];
            }
            ps[row][col] = v;
        }
    }
    __syncthreads();
    const int r = tid >> 5, cc = tid & 31;
    const int h = h0 + r, w = w0 + cc;
    if (h < HC && w < WC) {
        float s = 0.f;
        #pragma unroll
        for (int u = 0; u < 8; ++u)
            #pragma unroll
            for (int v2 = 0; v2 < 8; ++v2)
                s += wd[u * 8 + v2] * ps[r + u][cc + v2];
        const float inv = gamma[c] * rsqrtf(var[c] + 1e-5f);
        Yb[((b * CD + c) * HC + h) * WC + w] = __float2bfloat16(s * inv + (beta[c] - mean[c] * inv));
    }
}

// ---------------- Kernel D: pointwise 1x1 conv, bf16 MFMA, K=256 -------------
__global__ __launch_bounds__(256) void pw_mfma(
    const u16* __restrict__ Y, const u16* __restrict__ WP,
    float* __restrict__ O)
{
    __shared__ u16 As[4096];
    __shared__ u16 Bs[128 * 40];

    const int wt = blockIdx.x, ct = blockIdx.y, bh = blockIdx.z;
    const int h = bh % HC, b = bh / HC;
    const int w0 = wt * 128, co0 = ct * 128;
    const int tid = threadIdx.x;
    const int lane = tid & 63, wid = tid >> 6;
    const int wr = wid >> 1, wc = wid & 1;

    const int wl2 = (tid & 63) * 2;
    const int grp = tid >> 6;
    const int bw0 = wl2 * 40 + grp * 8;
    const int bw1 = bw0 + 40;

    const u16* yb = Y + ((size_t)(b * CD + grp * 8) * HC + h) * WC + (w0 + wl2);
    const u16* wpp = WP + (size_t)ct * 8 * 4096;

    f32x4 acc[4][4];
    #pragma unroll
    for (int m = 0; m < 4; ++m)
        #pragma unroll
        for (int n = 0; n < 4; ++n) acc[m][n] = (f32x4){0.f, 0.f, 0.f, 0.f};

    const int kb = lane >> 4;
    const int cq = lane & 15;

    for (int s = 0; s < 8; ++s) {
        u32x4 a0 = *(const u32x4*)(wpp + (size_t)s * 4096 + tid * 8);
        u32x4 a1 = *(const u32x4*)(wpp + (size_t)s * 4096 + (tid + 256) * 8);
        u32 r[8];
        #pragma unroll
        for (int j = 0; j < 8; ++j)
            r[j] = *(const u32*)(yb + (size_t)j * (HC * WC));
        yb += (size_t)32 * HC * WC;
        __syncthreads();
        *(u32x4*)&As[tid * 8] = a0;
        *(u32x4*)&As[(tid + 256) * 8] = a1;
        union { bf16x8 v; u32 u[4]; } p0, p1;
        #pragma unroll
        for (int q = 0; q < 4; ++q) {
            p0.u[q] = __builtin_amdgcn_perm(r[2 * q + 1], r[2 * q], 0x05040100u);
            p1.u[q] = __builtin_amdgcn_perm(r[2 * q + 1], r[2 * q], 0x07060302u);
        }
        *(bf16x8*)&Bs[bw0] = p0.v;
        *(bf16x8*)&Bs[bw1] = p1.v;
        __syncthreads();

        bf16x8 af[4], bfr[4];
        #pragma unroll
        for (int m = 0; m < 4; ++m)
            af[m] = *(const bf16x8*)&As[kb * 1024 + (wr * 64 + m * 16 + cq) * 8];
        #pragma unroll
        for (int n = 0; n < 4; ++n) {
            int wcol = wc * 64 + n * 16 + cq;
            bfr[n] = *(const bf16x8*)&Bs[wcol * 40 + kb * 8];
        }
        #pragma unroll
        for (int m = 0; m < 4; ++m)
            #pragma unroll
            for (int n = 0; n < 4; ++n)
                acc[m][n] = __builtin_amdgcn_mfma_f32_16x16x32_bf16(af[m], bfr[n], acc[m][n], 0, 0, 0);
    }

    const int rq = lane >> 4;
    #pragma unroll
    for (int m = 0; m < 4; ++m) {
        int cgb = co0 + wr * 64 + m * 16 + rq * 4;
        #pragma unroll
        for (int n = 0; n < 4; ++n) {
            int wg = w0 + wc * 64 + n * 16 + cq;
            if (wg < WC) {
                #pragma unroll
                for (int rr = 0; rr < 4; ++rr)
                    O[((size_t)(b * CD + cgb + rr) * HC + h) * WC + wg] = acc[m][n][rr];
            }
        }
    }
}

extern "C" void kernel_launch(void* const* d_in, const int* in_sizes, int n_in,
                              void* d_out, int out_size, void* d_ws, size_t ws_size,
                              hipStream_t stream)
{
    const float* x      = (const float*)d_in[0];
    const float* w_qkv  = (const float*)d_in[1];
    const float* bias_t = (const float*)d_in[2];
    const float* w_h    = (const float*)d_in[3];
    const float* b_h    = (const float*)d_in[4];
    const float* w_v    = (const float*)d_in[5];
    const float* b_v    = (const float*)d_in[6];
    const float* w_dw   = (const float*)d_in[7];
    const float* bn_g   = (const float*)d_in[8];
    const float* bn_b   = (const float*)d_in[9];
    const float* bn_m   = (const float*)d_in[10];
    const float* bn_v   = (const float*)d_in[11];
    const float* w_pw   = (const float*)d_in[12];
    float* out = (float*)d_out;

    u16* wsu = (u16*)d_ws;
    const u16* XPu = wsu;
    const u16* ZPu = wsu + ZP_OFF / 2;
    const u16* WTu = wsu + WT_OFF / 2;
    const u16* WPu = wsu + WPW_OFF / 2;
    const u16* WQu = wsu + WQ_OFF / 2;
    const float* BFu = (const float*)(wsu + BIAS_OFF / 2);

    // wprep -> attn(MFMA) -> halo -> sepconv(MFMA) -> dwbn -> pw(MFMA)
    wprep_kernel<<<5984, 256, 0, stream>>>(w_h, w_v, w_pw, w_qkv, bias_t, wsu);
    attn_mfma<<<2048, 512, 0, stream>>>(x, WQu, BFu, wsu);
    halo_kernel<<<6048, 256, 0, stream>>>(wsu);
    sepconv_mfma<<<dim3(2, 2, 2 * HC), 256, 0, stream>>>(XPu, WTu, ZPu, b_h, b_v, out);
    dwbn_kernel<<<dim3(8, 32, 512), 256, 0, stream>>>(out, w_dw, bn_g, bn_b, bn_m, bn_v,
                                                      (__hip_bfloat16*)d_ws);
    pw_mfma<<<dim3(2, 2, 2 * HC), 256, 0, stream>>>(wsu, WPu, out);
}

// Round 4
// 839.301 us; speedup vs baseline: 7.7959x; 1.0958x over previous
//
#include <hip/hip_runtime.h>
#include <hip/hip_bf16.h>

#define HC 252
#define WC 252
#define CD 256
#define NHEADS 16

// XP padded image: [b][ci][h 0..251][wp 0..263], wp = w_img + 4
#define XP_W 264
#define XP_HW (252*264)
#define XP_CHW (256*252*264)

typedef unsigned short u16;
typedef unsigned int u32;
typedef __attribute__((ext_vector_type(8))) short bf16x8;
typedef __attribute__((ext_vector_type(4))) float f32x4;
typedef __attribute__((ext_vector_type(4))) u32 u32x4;
typedef __attribute__((ext_vector_type(2))) u32 u32x2;

// ---- workspace layout (bytes) ----
#define XP_BYTES (2u * (unsigned)XP_CHW * 2u)      // 68,124,672
#define ZP_OFF   XP_BYTES
#define ZP_BYTES 409600u
#define WT_OFF   (ZP_OFF + ZP_BYTES)
#define WT_ELEMS (128*8192)                        // 1,048,576 bf16 (s,kb,co,8)
#define WPW_OFF  (WT_OFF + (unsigned)WT_ELEMS*2u)
#define WPW_ELEMS (8*8192)                         // 65,536 bf16
#define WQ_OFF   (WPW_OFF + (unsigned)WPW_ELEMS*2u)
#define WQ_ELEMS (768*256)                         // 196,608 bf16
#define BIAS_OFF (WQ_OFF + (unsigned)WQ_ELEMS*2u)

__device__ __forceinline__ u16 bfu(float f) {
    __hip_bfloat16 h = __float2bfloat16(f);
    return *(reinterpret_cast<u16*>(&h));
}
__device__ __forceinline__ u32 pack2(float a, float b) {
    return (u32)bfu(a) | ((u32)bfu(b) << 16);
}

// ---------------- Kernel A: fused qkv + window attention (MFMA) --------------
// grid 2048 = (b:2, wy:32, wx:32), 512 threads (8 waves, 2 heads/wave).
__global__ __launch_bounds__(512, 2) void attn_mfma(
    const float* __restrict__ x, const u16* __restrict__ WQ,
    const float* __restrict__ BIASF, u16* __restrict__ xp)
{
    __shared__ __align__(16) char smem[131072];

    const int blk = blockIdx.x;
    const int wx = blk & 31, wy = (blk >> 5) & 31, b = blk >> 10;
    const int tid = threadIdx.x;
    const int lane = tid & 63, wid = tid >> 6;
    const int g = lane >> 4, li = lane & 15;

    // ---- stage Xwin (fp32 x -> bf16 LDS, transposed, reflect-padded) ----
    {
        int ci = tid >> 1;
        int rbase = (tid & 1) * 4;
        const float* srcc = x + (size_t)(b * 256 + ci) * (HC * WC);
        #pragma unroll
        for (int rr = 0; rr < 4; ++rr) {
            int r = rbase + rr;
            int h = wy * 8 + r; if (h >= HC) h = 2 * HC - 2 - h;
            const float* src = srcc + h * WC;
            float v[8];
            if (wx == 31) {
                #pragma unroll
                for (int c = 0; c < 8; ++c) {
                    int w = 248 + c; if (w >= WC) w = 2 * WC - 2 - w;
                    v[c] = src[w];
                }
            } else {
                float4 f0 = *(const float4*)(src + wx * 8);
                float4 f1 = *(const float4*)(src + wx * 8 + 4);
                v[0]=f0.x; v[1]=f0.y; v[2]=f0.z; v[3]=f0.w;
                v[4]=f1.x; v[5]=f1.y; v[6]=f1.z; v[7]=f1.w;
            }
            #pragma unroll
            for (int c = 0; c < 8; ++c) {
                int pos = r * 8 + c;
                int byte = pos * 512 + ((ci * 2) ^ ((pos & 7) << 4));
                *(u16*)(smem + byte) = bfu(v[c]);
            }
        }
    }
    __syncthreads();

    const int QKVB = 32768 + wid * 12288;

    f32x4 acc[6][4];
    #pragma unroll
    for (int m = 0; m < 6; ++m)
        #pragma unroll
        for (int nf = 0; nf < 4; ++nf) acc[m][nf] = (f32x4){0.f,0.f,0.f,0.f};

    for (int ks = 0; ks < 8; ++ks) {
        bf16x8 bx[4];
        #pragma unroll
        for (int nf = 0; nf < 4; ++nf) {
            int pos = 16 * nf + li;
            int byte = pos * 512 + ((ks * 64 + 16 * g) ^ ((pos & 7) << 4));
            bx[nf] = *(const bf16x8*)(smem + byte);
        }
        #pragma unroll
        for (int m = 0; m < 6; ++m) {
            int p = m >> 1, hh2 = m & 1;
            int o = p * 256 + 32 * wid + 16 * hh2 + li;
            bf16x8 aw = *(const bf16x8*)(WQ + o * 256 + ks * 32 + 8 * g);
            #pragma unroll
            for (int nf = 0; nf < 4; ++nf)
                acc[m][nf] = __builtin_amdgcn_mfma_f32_16x16x32_bf16(aw, bx[nf], acc[m][nf], 0, 0, 0);
        }
    }
    __syncthreads();

    #pragma unroll
    for (int m = 0; m < 6; ++m) {
        int p = m >> 1, hh2 = m & 1;
        if (p < 2) {
            char* base = smem + QKVB + p * 4096 + hh2 * 2048;
            #pragma unroll
            for (int nf = 0; nf < 4; ++nf) {
                int pos = 16 * nf + li;
                u32 lo = pack2(acc[m][nf][0], acc[m][nf][1]);
                u32 hi = pack2(acc[m][nf][2], acc[m][nf][3]);
                int byte = pos * 32 + ((8 * g) ^ (((pos >> 2) & 1) << 4));
                *(u32x2*)(base + byte) = (u32x2){lo, hi};
            }
        } else {
            char* base = smem + QKVB + 8192 + hh2 * 2048;
            #pragma unroll
            for (int nf = 0; nf < 4; ++nf) {
                int pos = 16 * nf + li;
                #pragma unroll
                for (int r = 0; r < 4; ++r) {
                    int d = 4 * g + r;
                    int byte = (pos >> 3) * 256 + d * 16 + (pos & 7) * 2;
                    *(u16*)(base + byte) = bfu(acc[m][nf][r]);
                }
            }
        }
    }

    const bf16x8 zf = {0,0,0,0,0,0,0,0};

    for (int hh2 = 0; hh2 < 2; ++hh2) {
        const int head = 2 * wid + hh2;
        const char* Qb = smem + QKVB + hh2 * 2048;
        const char* Kb = smem + QKVB + 4096 + hh2 * 2048;
        const char* Vb = smem + QKVB + 8192 + hh2 * 2048;
        char* Pb = smem + wid * 4096;

        f32x4 s[4][4];
        #pragma unroll
        for (int mf = 0; mf < 4; ++mf)
            #pragma unroll
            for (int nf = 0; nf < 4; ++nf) s[mf][nf] = (f32x4){0.f,0.f,0.f,0.f};
        bf16x8 bk[4];
        #pragma unroll
        for (int nf = 0; nf < 4; ++nf) {
            int pos = 16 * nf + li;
            bk[nf] = (g < 2) ? *(const bf16x8*)(Kb + pos * 32 + ((16 * g) ^ (((pos >> 2) & 1) << 4))) : zf;
        }
        #pragma unroll
        for (int mf = 0; mf < 4; ++mf) {
            int pos = 16 * mf + li;
            bf16x8 aq = (g < 2) ? *(const bf16x8*)(Qb + pos * 32 + ((16 * g) ^ (((pos >> 2) & 1) << 4))) : zf;
            #pragma unroll
            for (int nf = 0; nf < 4; ++nf)
                s[mf][nf] = __builtin_amdgcn_mfma_f32_16x16x32_bf16(aq, bk[nf], s[mf][nf], 0, 0, 0);
        }

        f32x4 e[4][4];
        f32x4 rs[4];
        #pragma unroll
        for (int mf = 0; mf < 4; ++mf) rs[mf] = (f32x4){0.f,0.f,0.f,0.f};
        #pragma unroll
        for (int mf = 0; mf < 4; ++mf)
            #pragma unroll
            for (int nf = 0; nf < 4; ++nf) {
                f32x4 b4 = *(const f32x4*)(BIASF + (((head * 4 + mf) * 4 + nf) * 64 + lane) * 4);
                #pragma unroll
                for (int r = 0; r < 4; ++r) {
                    float ev = __expf(s[mf][nf][r] * 0.25f + b4[r]);
                    e[mf][nf][r] = ev;
                    rs[mf][r] += ev;
                }
            }
        #pragma unroll
        for (int mf = 0; mf < 4; ++mf)
            #pragma unroll
            for (int r = 0; r < 4; ++r) {
                float t = rs[mf][r];
                t += __shfl_xor(t, 1); t += __shfl_xor(t, 2);
                t += __shfl_xor(t, 4); t += __shfl_xor(t, 8);
                rs[mf][r] = t;
            }

        f32x4 o[4];
        #pragma unroll
        for (int mf = 0; mf < 4; ++mf) o[mf] = (f32x4){0.f,0.f,0.f,0.f};
        const bool even = !(lane & 1);
        #pragma unroll
        for (int hf = 0; hf < 2; ++hf) {
            #pragma unroll
            for (int mf = 0; mf < 4; ++mf)
                #pragma unroll
                for (int nfl = 0; nfl < 2; ++nfl) {
                    f32x4 ee = e[mf][2 * hf + nfl];
                    float p0 = __shfl_xor(ee[0], 1), p1 = __shfl_xor(ee[1], 1);
                    float p2 = __shfl_xor(ee[2], 1), p3 = __shfl_xor(ee[3], 1);
                    int jl = 16 * nfl + (li & ~1);
                    u32 w0, w1; int r0;
                    if (even) { w0 = pack2(ee[0], p0); w1 = pack2(ee[1], p1); r0 = 0; }
                    else      { w0 = pack2(p2, ee[2]); w1 = pack2(p3, ee[3]); r0 = 2; }
                    int i0 = 16 * mf + 4 * g + r0, i1 = i0 + 1;
                    *(u32*)(Pb + i0 * 64 + ((2 * jl) ^ ((i0 & 3) << 4))) = w0;
                    *(u32*)(Pb + i1 * 64 + ((2 * jl) ^ ((i1 & 3) << 4))) = w1;
                }
            bf16x8 bv = *(const bf16x8*)(Vb + (4 * hf + g) * 256 + li * 16);
            #pragma unroll
            for (int mf = 0; mf < 4; ++mf) {
                int i = 16 * mf + li;
                bf16x8 ap = *(const bf16x8*)(Pb + i * 64 + ((16 * g) ^ ((i & 3) << 4)));
                o[mf] = __builtin_amdgcn_mfma_f32_16x16x32_bf16(ap, bv, o[mf], 0, 0, 0);
            }
        }

        #pragma unroll
        for (int mf = 0; mf < 4; ++mf) {
            int h = wy * 8 + 2 * mf + (g >> 1);
            int wbase = wx * 8 + 4 * (g & 1);
            if (h < HC && wbase < WC) {
                float v0 = o[mf][0] / rs[mf][0], v1 = o[mf][1] / rs[mf][1];
                float v2 = o[mf][2] / rs[mf][2], v3 = o[mf][3] / rs[mf][3];
                size_t idx = ((size_t)(b * 256 + head * 16 + li) * HC + h) * XP_W + wbase + 4;
                *(u32x2*)(xp + idx) = (u32x2){pack2(v0, v1), pack2(v2, v3)};
            }
        }
    }
}

// ---------------- weight prep: WT2, WP2, ZP, WQ(bf16), BIASF -----------------
__global__ __launch_bounds__(256) void wprep_kernel(
    const float* __restrict__ wh, const float* __restrict__ wv,
    const float* __restrict__ wpw, const float* __restrict__ wqkv,
    const float* __restrict__ btab, u16* __restrict__ wsu)
{
    int i = blockIdx.x * 256 + threadIdx.x;
    u16* WT = wsu + WT_OFF / 2;
    u16* WP = wsu + WPW_OFF / 2;
    u16* ZP = wsu + ZP_OFF / 2;
    u16* WQp = wsu + WQ_OFF / 2;
    float* BF = (float*)(wsu + BIAS_OFF / 2);
    if (i < WT_ELEMS) {
        // WT2[s][kb][co][8]: k = s*32 + kb*8 + j
        int j = i & 7, co = (i >> 3) & 255, kb = (i >> 11) & 3, s = i >> 13;
        float v = (s < 64) ? wh[co * 2048 + s * 32 + kb * 8 + j]
                           : wv[co * 2048 + (s - 64) * 32 + kb * 8 + j];
        WT[i] = bfu(v);
    } else if (i < WT_ELEMS + WPW_ELEMS) {
        int i2 = i - WT_ELEMS;
        int j = i2 & 7, co = (i2 >> 3) & 255, kb = (i2 >> 11) & 3, s = i2 >> 13;
        WP[i2] = bfu(wpw[co * 256 + s * 32 + kb * 8 + j]);
    } else if (i < WT_ELEMS + WPW_ELEMS + (int)(ZP_BYTES / 2)) {
        ZP[i - WT_ELEMS - WPW_ELEMS] = 0;
    } else if (i < WT_ELEMS + WPW_ELEMS + (int)(ZP_BYTES / 2) + WQ_ELEMS) {
        int i4 = i - WT_ELEMS - WPW_ELEMS - (int)(ZP_BYTES / 2);
        WQp[i4] = bfu(wqkv[i4]);
    } else {
        int i5 = i - WT_ELEMS - WPW_ELEMS - (int)(ZP_BYTES / 2) - WQ_ELEMS;
        if (i5 < 16384) {
            int lane = i5 & 63, nf = (i5 >> 6) & 3, mf = (i5 >> 8) & 3, head = i5 >> 10;
            int gg = lane >> 4, ll = lane & 15;
            #pragma unroll
            for (int r = 0; r < 4; ++r) {
                int row = 16 * mf + 4 * gg + r;
                int col = 16 * nf + ll;
                int dy = (row >> 3) - (col >> 3) + 7;
                int dx = (row & 7) - (col & 7) + 7;
                BF[i5 * 4 + r] = btab[(dy * 15 + dx) * NHEADS + head];
            }
        }
    }
}

// ---------------- halo fill for XP: wp 0..3, 256..263 ------------------------
__global__ __launch_bounds__(256) void halo_kernel(u16* __restrict__ xp)
{
    int i = blockIdx.x * 256 + threadIdx.x;
    if (i >= 129024 * 12) return;
    int row = i / 12, c = i % 12;
    int wp = (c < 4) ? c : 252 + c;
    u16 v = 0;
    if (wp == 256) v = xp[row * XP_W + 254];
    xp[row * XP_W + wp] = v;
}

// ---------------- Kernel B: sepconv bf16 MFMA, K=4096, pipelined -------------
// grid 504 = (b,h), XCD-swizzled. Block: 256co x 256w, 4 waves of 128x128.
__global__ __launch_bounds__(256, 1) void sepconv_mfma(
    const u16* __restrict__ xp, const u16* __restrict__ WT,
    const u16* __restrict__ ZP,
    const float* __restrict__ b_h, const float* __restrict__ b_v,
    float* __restrict__ P)
{
    __shared__ u16 As[2][8192];       // [kb][co][8]
    __shared__ u16 Bs[2][256 * 40];   // [w][kk], rows padded to 40 u16

    const int bid = blockIdx.x;                   // 504 = 8*63, bijective swizzle
    const int zz = (bid & 7) * 63 + (bid >> 3);
    const int h = zz % HC, b = zz / HC;
    const int tid = threadIdx.x;
    const int lane = tid & 63, wid = tid >> 6;
    const int wr = wid >> 1, wc = wid & 1;
    const int cq = lane & 15, kb = lane >> 4;

    const int wl2 = (tid & 127) * 2;              // w pair
    const int oc0 = tid >> 7;                     // octets oc0, oc0+2

    const u16* hcur[8];
    int hstep[8];
    #pragma unroll
    for (int t = 0; t < 8; ++t) {
        int j = h + t - 3;
        bool valid = (j >= 0 && j <= 252);
        int jr = (j == 252) ? 250 : j;
        hcur[t] = valid ? (xp + (size_t)b * XP_CHW + (size_t)jr * XP_W) : ZP;
        hstep[t] = valid ? 4 * XP_HW : 0;
    }
    const u16* vbase = xp + (size_t)b * XP_CHW + (size_t)h * XP_W;

    f32x4 acc[8][8];
    #pragma unroll
    for (int m = 0; m < 8; ++m)
        #pragma unroll
        for (int n = 0; n < 8; ++n) acc[m][n] = (f32x4){0.f, 0.f, 0.f, 0.f};

    u32x4 rA[4];
    u32 rB[2][8];

    // ---- prologue: load + write step 0 ----
    #pragma unroll
    for (int c = 0; c < 4; ++c)
        rA[c] = *(const u32x4*)(WT + (size_t)(c * 256 + tid) * 8);
    #pragma unroll
    for (int g2 = 0; g2 < 2; ++g2) {
        int oc = oc0 + 2 * g2;
        int off = oc * XP_HW + wl2 + 4;
        #pragma unroll
        for (int t = 0; t < 8; ++t)
            rB[g2][t] = *(const u32*)(hcur[t] + off);
    }
    #pragma unroll
    for (int c = 0; c < 4; ++c)
        *(u32x4*)&As[0][(c * 256 + tid) * 8] = rA[c];
    #pragma unroll
    for (int g2 = 0; g2 < 2; ++g2) {
        int oc = oc0 + 2 * g2;
        union { bf16x8 v; u32 u[4]; } p0, p1;
        #pragma unroll
        for (int q = 0; q < 4; ++q) {
            p0.u[q] = __builtin_amdgcn_perm(rB[g2][2 * q + 1], rB[g2][2 * q], 0x05040100u);
            p1.u[q] = __builtin_amdgcn_perm(rB[g2][2 * q + 1], rB[g2][2 * q], 0x07060302u);
        }
        *(bf16x8*)&Bs[0][wl2 * 40 + oc * 8] = p0.v;
        *(bf16x8*)&Bs[0][(wl2 + 1) * 40 + oc * 8] = p1.v;
    }

    for (int s = 0; s < 128; ++s) {
        const int cur = s & 1;
        const int s1 = s + 1;
        const bool hph1 = (s1 < 64);
        if (s1 < 128) {
            #pragma unroll
            for (int c = 0; c < 4; ++c)
                rA[c] = *(const u32x4*)(WT + (size_t)s1 * 8192 + (size_t)(c * 256 + tid) * 8);
            if (hph1) {
                #pragma unroll
                for (int t = 0; t < 8; ++t) hcur[t] += hstep[t];
                #pragma unroll
                for (int g2 = 0; g2 < 2; ++g2) {
                    int oc = oc0 + 2 * g2;
                    int off = oc * XP_HW + wl2 + 4;
                    #pragma unroll
                    for (int t = 0; t < 8; ++t)
                        rB[g2][t] = *(const u32*)(hcur[t] + off);
                }
            } else {
                #pragma unroll
                for (int g2 = 0; g2 < 2; ++g2) {
                    int oc = oc0 + 2 * g2;
                    int off = ((s1 - 64) * 4 + oc) * XP_HW + wl2;
                    #pragma unroll
                    for (int l = 0; l < 6; ++l)
                        rB[g2][l] = *(const u32*)(vbase + off + 2 * l);
                }
            }
        }
        __syncthreads();

        bf16x8 af[8], bfr[8];
        #pragma unroll
        for (int m = 0; m < 8; ++m)
            af[m] = *(const bf16x8*)&As[cur][kb * 2048 + (wr * 128 + m * 16 + cq) * 8];
        #pragma unroll
        for (int n = 0; n < 8; ++n)
            bfr[n] = *(const bf16x8*)&Bs[cur][(wc * 128 + n * 16 + cq) * 40 + kb * 8];
        #pragma unroll
        for (int m = 0; m < 8; ++m)
            #pragma unroll
            for (int n = 0; n < 8; ++n)
                acc[m][n] = __builtin_amdgcn_mfma_f32_16x16x32_bf16(af[m], bfr[n], acc[m][n], 0, 0, 0);

        if (s1 < 128) {
            const int nxt = cur ^ 1;
            #pragma unroll
            for (int c = 0; c < 4; ++c)
                *(u32x4*)&As[nxt][(c * 256 + tid) * 8] = rA[c];
            #pragma unroll
            for (int g2 = 0; g2 < 2; ++g2) {
                int oc = oc0 + 2 * g2;
                union { bf16x8 v; u32 u[4]; } p0, p1;
                if (hph1) {
                    #pragma unroll
                    for (int q = 0; q < 4; ++q) {
                        p0.u[q] = __builtin_amdgcn_perm(rB[g2][2 * q + 1], rB[g2][2 * q], 0x05040100u);
                        p1.u[q] = __builtin_amdgcn_perm(rB[g2][2 * q + 1], rB[g2][2 * q], 0x07060302u);
                    }
                } else {
                    #pragma unroll
                    for (int q = 0; q < 4; ++q)
                        p0.u[q] = __builtin_amdgcn_alignbit(rB[g2][q + 1], rB[g2][q], 16);
                    p1.u[0] = rB[g2][1]; p1.u[1] = rB[g2][2];
                    p1.u[2] = rB[g2][3]; p1.u[3] = rB[g2][4];
                }
                *(bf16x8*)&Bs[nxt][wl2 * 40 + oc * 8] = p0.v;
                *(bf16x8*)&Bs[nxt][(wl2 + 1) * 40 + oc * 8] = p1.v;
            }
        }
    }

    // ---- epilogue: bias + fp32 store ----
    const int rq = lane >> 4, cc = lane & 15;
    #pragma unroll
    for (int m = 0; m < 8; ++m) {
        int cgb = wr * 128 + m * 16 + rq * 4;
        float bias[4];
        #pragma unroll
        for (int rr = 0; rr < 4; ++rr) bias[rr] = b_h[cgb + rr] + b_v[cgb + rr];
        #pragma unroll
        for (int n = 0; n < 8; ++n) {
            int wg = wc * 128 + n * 16 + cc;
            if (wg < WC) {
                #pragma unroll
                for (int rr = 0; rr < 4; ++rr)
                    P[((size_t)(b * CD + cgb + rr) * HC + h) * WC + wg] = acc[m][n][rr] + bias[rr];
            }
        }
    }
}

// ---------------- Kernel C: depthwise 8x8 conv + BN -> bf16 Y ----------------
__global__ __launch_bounds__(256) void dwbn_kernel(
    const float* __restrict__ P, const float* __restrict__ w_dw,
    const float* __restrict__ gamma, const float* __restrict__ beta,
    const float* __restrict__ mean, const float* __restrict__ var,
    __hip_bfloat16* __restrict__ Yb)
{
    __shared__ float ps[15][42];
    __shared__ float wd[64];
    const int bw = blockIdx.x, bh = blockIdx.y, bz = blockIdx.z;
    const int b = bz >> 8, c = bz & 255;
    const int h0 = bh * 8, w0 = bw * 32;
    const int tid = threadIdx.x;
    if (tid < 64) wd[tid] = w_dw[c * 64 + tid];
    for (int it = 0; it < 3; ++it) {
        int flat = tid + it * 256;
        if (flat < 630) {
            int row = flat / 42, col = flat % 42;
            int j = h0 - 3 + row, wcol = w0 - 3 + col;
            float v = 0.f;
            if (j >= 0 && j <= HC && wcol >= 0 && wcol <= WC) {
                int jr = (j == HC) ? (HC - 2) : j;
                int wr2 = (wcol == WC) ? (WC - 2) : wcol;
                v = P[((b * CD + c) * HC + jr) * WC + wr2];
            }
            ps[row][col] = v;
        }
    }
    __syncthreads();
    const int r = tid >> 5, cc = tid & 31;
    const int h = h0 + r, w = w0 + cc;
    if (h < HC && w < WC) {
        float s = 0.f;
        #pragma unroll
        for (int u = 0; u < 8; ++u)
            #pragma unroll
            for (int v2 = 0; v2 < 8; ++v2)
                s += wd[u * 8 + v2] * ps[r + u][cc + v2];
        const float inv = gamma[c] * rsqrtf(var[c] + 1e-5f);
        Yb[((b * CD + c) * HC + h) * WC + w] = __float2bfloat16(s * inv + (beta[c] - mean[c] * inv));
    }
}

// ---------------- Kernel D: pointwise 1x1, bf16 MFMA, K=256, pipelined -------
// grid 504 = (b,h), XCD-swizzled. Block: 256co x 256w, 4 waves of 128x128.
__global__ __launch_bounds__(256, 1) void pw_mfma(
    const u16* __restrict__ Y, const u16* __restrict__ WP,
    float* __restrict__ O)
{
    __shared__ u16 As[2][8192];
    __shared__ u16 Bs[2][256 * 40];

    const int bid = blockIdx.x;
    const int zz = (bid & 7) * 63 + (bid >> 3);
    const int h = zz % HC, b = zz / HC;
    const int tid = threadIdx.x;
    const int lane = tid & 63, wid = tid >> 6;
    const int wr = wid >> 1, wc = wid & 1;
    const int cq = lane & 15, kb = lane >> 4;

    const int wl2 = (tid & 127) * 2;
    const int oc0 = tid >> 7;

    const u16* yb = Y + ((size_t)(b * 256) * HC + h) * WC + wl2;

    f32x4 acc[8][8];
    #pragma unroll
    for (int m = 0; m < 8; ++m)
        #pragma unroll
        for (int n = 0; n < 8; ++n) acc[m][n] = (f32x4){0.f, 0.f, 0.f, 0.f};

    u32x4 rA[4];
    u32 rB[2][8];

    #pragma unroll
    for (int c = 0; c < 4; ++c)
        rA[c] = *(const u32x4*)(WP + (size_t)(c * 256 + tid) * 8);
    #pragma unroll
    for (int g2 = 0; g2 < 2; ++g2) {
        int oc = oc0 + 2 * g2;
        #pragma unroll
        for (int j = 0; j < 8; ++j)
            rB[g2][j] = *(const u32*)(yb + (size_t)(oc * 8 + j) * (HC * WC));
    }
    #pragma unroll
    for (int c = 0; c < 4; ++c)
        *(u32x4*)&As[0][(c * 256 + tid) * 8] = rA[c];
    #pragma unroll
    for (int g2 = 0; g2 < 2; ++g2) {
        int oc = oc0 + 2 * g2;
        union { bf16x8 v; u32 u[4]; } p0, p1;
        #pragma unroll
        for (int q = 0; q < 4; ++q) {
            p0.u[q] = __builtin_amdgcn_perm(rB[g2][2 * q + 1], rB[g2][2 * q], 0x05040100u);
            p1.u[q] = __builtin_amdgcn_perm(rB[g2][2 * q + 1], rB[g2][2 * q], 0x07060302u);
        }
        *(bf16x8*)&Bs[0][wl2 * 40 + oc * 8] = p0.v;
        *(bf16x8*)&Bs[0][(wl2 + 1) * 40 + oc * 8] = p1.v;
    }

    for (int s = 0; s < 8; ++s) {
        const int cur = s & 1;
        const int s1 = s + 1;
        if (s1 < 8) {
            #pragma unroll
            for (int c = 0; c < 4; ++c)
                rA[c] = *(const u32x4*)(WP + (size_t)s1 * 8192 + (size_t)(c * 256 + tid) * 8);
            #pragma unroll
            for (int g2 = 0; g2 < 2; ++g2) {
                int oc = oc0 + 2 * g2;
                #pragma unroll
                for (int j = 0; j < 8; ++j)
                    rB[g2][j] = *(const u32*)(yb + (size_t)(s1 * 32 + oc * 8 + j) * (HC * WC));
            }
        }
        __syncthreads();

        bf16x8 af[8], bfr[8];
        #pragma unroll
        for (int m = 0; m < 8; ++m)
            af[m] = *(const bf16x8*)&As[cur][kb * 2048 + (wr * 128 + m * 16 + cq) * 8];
        #pragma unroll
        for (int n = 0; n < 8; ++n)
            bfr[n] = *(const bf16x8*)&Bs[cur][(wc * 128 + n * 16 + cq) * 40 + kb * 8];
        #pragma unroll
        for (int m = 0; m < 8; ++m)
            #pragma unroll
            for (int n = 0; n < 8; ++n)
                acc[m][n] = __builtin_amdgcn_mfma_f32_16x16x32_bf16(af[m], bfr[n], acc[m][n], 0, 0, 0);

        if (s1 < 8) {
            const int nxt = cur ^ 1;
            #pragma unroll
            for (int c = 0; c < 4; ++c)
                *(u32x4*)&As[nxt][(c * 256 + tid) * 8] = rA[c];
            #pragma unroll
            for (int g2 = 0; g2 < 2; ++g2) {
                int oc = oc0 + 2 * g2;
                union { bf16x8 v; u32 u[4]; } p0, p1;
                #pragma unroll
                for (int q = 0; q < 4; ++q) {
                    p0.u[q] = __builtin_amdgcn_perm(rB[g2][2 * q + 1], rB[g2][2 * q], 0x05040100u);
                    p1.u[q] = __builtin_amdgcn_perm(rB[g2][2 * q + 1], rB[g2][2 * q], 0x07060302u);
                }
                *(bf16x8*)&Bs[nxt][wl2 * 40 + oc * 8] = p0.v;
                *(bf16x8*)&Bs[nxt][(wl2 + 1) * 40 + oc * 8] = p1.v;
            }
        }
    }

    const int rq = lane >> 4, cc = lane & 15;
    #pragma unroll
    for (int m = 0; m < 8; ++m) {
        int cgb = wr * 128 + m * 16 + rq * 4;
        #pragma unroll
        for (int n = 0; n < 8; ++n) {
            int wg = wc * 128 + n * 16 + cc;
            if (wg < WC) {
                #pragma unroll
                for (int rr = 0; rr < 4; ++rr)
                    O[((size_t)(b * CD + cgb + rr) * HC + h) * WC + wg] = acc[m][n][rr];
            }
        }
    }
}

extern "C" void kernel_launch(void* const* d_in, const int* in_sizes, int n_in,
                              void* d_out, int out_size, void* d_ws, size_t ws_size,
                              hipStream_t stream)
{
    const float* x      = (const float*)d_in[0];
    const float* w_qkv  = (const float*)d_in[1];
    const float* bias_t = (const float*)d_in[2];
    const float* w_h    = (const float*)d_in[3];
    const float* b_h    = (const float*)d_in[4];
    const float* w_v    = (const float*)d_in[5];
    const float* b_v    = (const float*)d_in[6];
    const float* w_dw   = (const float*)d_in[7];
    const float* bn_g   = (const float*)d_in[8];
    const float* bn_b   = (const float*)d_in[9];
    const float* bn_m   = (const float*)d_in[10];
    const float* bn_v   = (const float*)d_in[11];
    const float* w_pw   = (const float*)d_in[12];
    float* out = (float*)d_out;

    u16* wsu = (u16*)d_ws;
    const u16* XPu = wsu;
    const u16* ZPu = wsu + ZP_OFF / 2;
    const u16* WTu = wsu + WT_OFF / 2;
    const u16* WPu = wsu + WPW_OFF / 2;
    const u16* WQu = wsu + WQ_OFF / 2;
    const float* BFu = (const float*)(wsu + BIAS_OFF / 2);

    // wprep -> attn(MFMA) -> halo -> sepconv(MFMA) -> dwbn -> pw(MFMA)
    wprep_kernel<<<5984, 256, 0, stream>>>(w_h, w_v, w_pw, w_qkv, bias_t, wsu);
    attn_mfma<<<2048, 512, 0, stream>>>(x, WQu, BFu, wsu);
    halo_kernel<<<6048, 256, 0, stream>>>(wsu);
    sepconv_mfma<<<504, 256, 0, stream>>>(XPu, WTu, ZPu, b_h, b_v, out);
    dwbn_kernel<<<dim3(8, 32, 512), 256, 0, stream>>>(out, w_dw, bn_g, bn_b, bn_m, bn_v,
                                                      (__hip_bfloat16*)d_ws);
    pw_mfma<<<504, 256, 0, stream>>>(wsu, WPu, out);
}

// Round 5
// 769.857 us; speedup vs baseline: 8.4991x; 1.0902x over previous
//
#include <hip/hip_runtime.h>
#include <hip/hip_bf16.h>

#define HC 252
#define WC 252
#define CD 256
#define NHEADS 16

// XP padded image: [b][ci][h 0..251][wp 0..263], wp = w_img + 4
#define XP_W 264
#define XP_HW (252*264)
#define XP_CHW (256*252*264)

typedef unsigned short u16;
typedef unsigned int u32;
typedef __attribute__((ext_vector_type(8))) short bf16x8;
typedef __attribute__((ext_vector_type(4))) float f32x4;
typedef __attribute__((ext_vector_type(4))) u32 u32x4;
typedef __attribute__((ext_vector_type(2))) u32 u32x2;

// ---- workspace layout (bytes) ----
#define XP_BYTES (2u * (unsigned)XP_CHW * 2u)      // 68,124,672
#define ZP_OFF   XP_BYTES
#define ZP_BYTES 409600u
#define WT_OFF   (ZP_OFF + ZP_BYTES)
#define WT_ELEMS (128*8192)                        // 1,048,576 bf16 [s][kb][co][8]
#define WPW_OFF  (WT_OFF + (unsigned)WT_ELEMS*2u)
#define WPW_ELEMS (8*8192)                         // 65,536 bf16
#define WQ_OFF   (WPW_OFF + (unsigned)WPW_ELEMS*2u)
#define WQ_ELEMS (768*256)                         // 196,608 bf16
#define BIAS_OFF (WQ_OFF + (unsigned)WQ_ELEMS*2u)

__device__ __forceinline__ u16 bfu(float f) {
    __hip_bfloat16 h = __float2bfloat16(f);
    return *(reinterpret_cast<u16*>(&h));
}
__device__ __forceinline__ u32 pack2(float a, float b) {
    return (u32)bfu(a) | ((u32)bfu(b) << 16);
}

// ---------------- Kernel A: fused qkv + window attention (MFMA) --------------
// grid 2048 = (b:2, wy:32, wx:32), 512 threads (8 waves, 2 heads/wave).
__global__ __launch_bounds__(512, 2) void attn_mfma(
    const float* __restrict__ x, const u16* __restrict__ WQ,
    const float* __restrict__ BIASF, u16* __restrict__ xp)
{
    __shared__ __align__(16) char smem[131072];

    const int blk = blockIdx.x;
    const int wx = blk & 31, wy = (blk >> 5) & 31, b = blk >> 10;
    const int tid = threadIdx.x;
    const int lane = tid & 63, wid = tid >> 6;
    const int g = lane >> 4, li = lane & 15;

    // ---- stage Xwin (fp32 x -> bf16 LDS, transposed, reflect-padded) ----
    {
        int ci = tid >> 1;
        int rbase = (tid & 1) * 4;
        const float* srcc = x + (size_t)(b * 256 + ci) * (HC * WC);
        #pragma unroll
        for (int rr = 0; rr < 4; ++rr) {
            int r = rbase + rr;
            int h = wy * 8 + r; if (h >= HC) h = 2 * HC - 2 - h;
            const float* src = srcc + h * WC;
            float v[8];
            if (wx == 31) {
                #pragma unroll
                for (int c = 0; c < 8; ++c) {
                    int w = 248 + c; if (w >= WC) w = 2 * WC - 2 - w;
                    v[c] = src[w];
                }
            } else {
                float4 f0 = *(const float4*)(src + wx * 8);
                float4 f1 = *(const float4*)(src + wx * 8 + 4);
                v[0]=f0.x; v[1]=f0.y; v[2]=f0.z; v[3]=f0.w;
                v[4]=f1.x; v[5]=f1.y; v[6]=f1.z; v[7]=f1.w;
            }
            #pragma unroll
            for (int c = 0; c < 8; ++c) {
                int pos = r * 8 + c;
                int byte = pos * 512 + ((ci * 2) ^ ((pos & 7) << 4));
                *(u16*)(smem + byte) = bfu(v[c]);
            }
        }
    }
    __syncthreads();

    const int QKVB = 32768 + wid * 12288;

    f32x4 acc[6][4];
    #pragma unroll
    for (int m = 0; m < 6; ++m)
        #pragma unroll
        for (int nf = 0; nf < 4; ++nf) acc[m][nf] = (f32x4){0.f,0.f,0.f,0.f};

    for (int ks = 0; ks < 8; ++ks) {
        bf16x8 bx[4];
        #pragma unroll
        for (int nf = 0; nf < 4; ++nf) {
            int pos = 16 * nf + li;
            int byte = pos * 512 + ((ks * 64 + 16 * g) ^ ((pos & 7) << 4));
            bx[nf] = *(const bf16x8*)(smem + byte);
        }
        #pragma unroll
        for (int m = 0; m < 6; ++m) {
            int p = m >> 1, hh2 = m & 1;
            int o = p * 256 + 32 * wid + 16 * hh2 + li;
            bf16x8 aw = *(const bf16x8*)(WQ + o * 256 + ks * 32 + 8 * g);
            #pragma unroll
            for (int nf = 0; nf < 4; ++nf)
                acc[m][nf] = __builtin_amdgcn_mfma_f32_16x16x32_bf16(aw, bx[nf], acc[m][nf], 0, 0, 0);
        }
    }
    __syncthreads();

    #pragma unroll
    for (int m = 0; m < 6; ++m) {
        int p = m >> 1, hh2 = m & 1;
        if (p < 2) {
            char* base = smem + QKVB + p * 4096 + hh2 * 2048;
            #pragma unroll
            for (int nf = 0; nf < 4; ++nf) {
                int pos = 16 * nf + li;
                u32 lo = pack2(acc[m][nf][0], acc[m][nf][1]);
                u32 hi = pack2(acc[m][nf][2], acc[m][nf][3]);
                int byte = pos * 32 + ((8 * g) ^ (((pos >> 2) & 1) << 4));
                *(u32x2*)(base + byte) = (u32x2){lo, hi};
            }
        } else {
            char* base = smem + QKVB + 8192 + hh2 * 2048;
            #pragma unroll
            for (int nf = 0; nf < 4; ++nf) {
                int pos = 16 * nf + li;
                #pragma unroll
                for (int r = 0; r < 4; ++r) {
                    int d = 4 * g + r;
                    int byte = (pos >> 3) * 256 + d * 16 + (pos & 7) * 2;
                    *(u16*)(base + byte) = bfu(acc[m][nf][r]);
                }
            }
        }
    }

    const bf16x8 zf = {0,0,0,0,0,0,0,0};

    for (int hh2 = 0; hh2 < 2; ++hh2) {
        const int head = 2 * wid + hh2;
        const char* Qb = smem + QKVB + hh2 * 2048;
        const char* Kb = smem + QKVB + 4096 + hh2 * 2048;
        const char* Vb = smem + QKVB + 8192 + hh2 * 2048;
        char* Pb = smem + wid * 4096;

        f32x4 s[4][4];
        #pragma unroll
        for (int mf = 0; mf < 4; ++mf)
            #pragma unroll
            for (int nf = 0; nf < 4; ++nf) s[mf][nf] = (f32x4){0.f,0.f,0.f,0.f};
        bf16x8 bk[4];
        #pragma unroll
        for (int nf = 0; nf < 4; ++nf) {
            int pos = 16 * nf + li;
            bk[nf] = (g < 2) ? *(const bf16x8*)(Kb + pos * 32 + ((16 * g) ^ (((pos >> 2) & 1) << 4))) : zf;
        }
        #pragma unroll
        for (int mf = 0; mf < 4; ++mf) {
            int pos = 16 * mf + li;
            bf16x8 aq = (g < 2) ? *(const bf16x8*)(Qb + pos * 32 + ((16 * g) ^ (((pos >> 2) & 1) << 4))) : zf;
            #pragma unroll
            for (int nf = 0; nf < 4; ++nf)
                s[mf][nf] = __builtin_amdgcn_mfma_f32_16x16x32_bf16(aq, bk[nf], s[mf][nf], 0, 0, 0);
        }

        f32x4 e[4][4];
        f32x4 rs[4];
        #pragma unroll
        for (int mf = 0; mf < 4; ++mf) rs[mf] = (f32x4){0.f,0.f,0.f,0.f};
        #pragma unroll
        for (int mf = 0; mf < 4; ++mf)
            #pragma unroll
            for (int nf = 0; nf < 4; ++nf) {
                f32x4 b4 = *(const f32x4*)(BIASF + (((head * 4 + mf) * 4 + nf) * 64 + lane) * 4);
                #pragma unroll
                for (int r = 0; r < 4; ++r) {
                    float ev = __expf(s[mf][nf][r] * 0.25f + b4[r]);
                    e[mf][nf][r] = ev;
                    rs[mf][r] += ev;
                }
            }
        #pragma unroll
        for (int mf = 0; mf < 4; ++mf)
            #pragma unroll
            for (int r = 0; r < 4; ++r) {
                float t = rs[mf][r];
                t += __shfl_xor(t, 1); t += __shfl_xor(t, 2);
                t += __shfl_xor(t, 4); t += __shfl_xor(t, 8);
                rs[mf][r] = t;
            }

        f32x4 o[4];
        #pragma unroll
        for (int mf = 0; mf < 4; ++mf) o[mf] = (f32x4){0.f,0.f,0.f,0.f};
        const bool even = !(lane & 1);
        #pragma unroll
        for (int hf = 0; hf < 2; ++hf) {
            #pragma unroll
            for (int mf = 0; mf < 4; ++mf)
                #pragma unroll
                for (int nfl = 0; nfl < 2; ++nfl) {
                    f32x4 ee = e[mf][2 * hf + nfl];
                    float p0 = __shfl_xor(ee[0], 1), p1 = __shfl_xor(ee[1], 1);
                    float p2 = __shfl_xor(ee[2], 1), p3 = __shfl_xor(ee[3], 1);
                    int jl = 16 * nfl + (li & ~1);
                    u32 w0, w1; int r0;
                    if (even) { w0 = pack2(ee[0], p0); w1 = pack2(ee[1], p1); r0 = 0; }
                    else      { w0 = pack2(p2, ee[2]); w1 = pack2(p3, ee[3]); r0 = 2; }
                    int i0 = 16 * mf + 4 * g + r0, i1 = i0 + 1;
                    *(u32*)(Pb + i0 * 64 + ((2 * jl) ^ ((i0 & 3) << 4))) = w0;
                    *(u32*)(Pb + i1 * 64 + ((2 * jl) ^ ((i1 & 3) << 4))) = w1;
                }
            bf16x8 bv = *(const bf16x8*)(Vb + (4 * hf + g) * 256 + li * 16);
            #pragma unroll
            for (int mf = 0; mf < 4; ++mf) {
                int i = 16 * mf + li;
                bf16x8 ap = *(const bf16x8*)(Pb + i * 64 + ((16 * g) ^ ((i & 3) << 4)));
                o[mf] = __builtin_amdgcn_mfma_f32_16x16x32_bf16(ap, bv, o[mf], 0, 0, 0);
            }
        }

        #pragma unroll
        for (int mf = 0; mf < 4; ++mf) {
            int h = wy * 8 + 2 * mf + (g >> 1);
            int wbase = wx * 8 + 4 * (g & 1);
            if (h < HC && wbase < WC) {
                float v0 = o[mf][0] / rs[mf][0], v1 = o[mf][1] / rs[mf][1];
                float v2 = o[mf][2] / rs[mf][2], v3 = o[mf][3] / rs[mf][3];
                size_t idx = ((size_t)(b * 256 + head * 16 + li) * HC + h) * XP_W + wbase + 4;
                *(u32x2*)(xp + idx) = (u32x2){pack2(v0, v1), pack2(v2, v3)};
            }
        }
    }
}

// ---------------- weight prep: WT2, WP2, ZP, WQ(bf16), BIASF -----------------
__global__ __launch_bounds__(256) void wprep_kernel(
    const float* __restrict__ wh, const float* __restrict__ wv,
    const float* __restrict__ wpw, const float* __restrict__ wqkv,
    const float* __restrict__ btab, u16* __restrict__ wsu)
{
    int i = blockIdx.x * 256 + threadIdx.x;
    u16* WT = wsu + WT_OFF / 2;
    u16* WP = wsu + WPW_OFF / 2;
    u16* ZP = wsu + ZP_OFF / 2;
    u16* WQp = wsu + WQ_OFF / 2;
    float* BF = (float*)(wsu + BIAS_OFF / 2);
    if (i < WT_ELEMS) {
        // WT2[s][kb][co][8]: k = s*32 + kb*8 + j
        int j = i & 7, co = (i >> 3) & 255, kb = (i >> 11) & 3, s = i >> 13;
        float v = (s < 64) ? wh[co * 2048 + s * 32 + kb * 8 + j]
                           : wv[co * 2048 + (s - 64) * 32 + kb * 8 + j];
        WT[i] = bfu(v);
    } else if (i < WT_ELEMS + WPW_ELEMS) {
        int i2 = i - WT_ELEMS;
        int j = i2 & 7, co = (i2 >> 3) & 255, kb = (i2 >> 11) & 3, s = i2 >> 13;
        WP[i2] = bfu(wpw[co * 256 + s * 32 + kb * 8 + j]);
    } else if (i < WT_ELEMS + WPW_ELEMS + (int)(ZP_BYTES / 2)) {
        ZP[i - WT_ELEMS - WPW_ELEMS] = 0;
    } else if (i < WT_ELEMS + WPW_ELEMS + (int)(ZP_BYTES / 2) + WQ_ELEMS) {
        int i4 = i - WT_ELEMS - WPW_ELEMS - (int)(ZP_BYTES / 2);
        WQp[i4] = bfu(wqkv[i4]);
    } else {
        int i5 = i - WT_ELEMS - WPW_ELEMS - (int)(ZP_BYTES / 2) - WQ_ELEMS;
        if (i5 < 16384) {
            int lane = i5 & 63, nf = (i5 >> 6) & 3, mf = (i5 >> 8) & 3, head = i5 >> 10;
            int gg = lane >> 4, ll = lane & 15;
            #pragma unroll
            for (int r = 0; r < 4; ++r) {
                int row = 16 * mf + 4 * gg + r;
                int col = 16 * nf + ll;
                int dy = (row >> 3) - (col >> 3) + 7;
                int dx = (row & 7) - (col & 7) + 7;
                BF[i5 * 4 + r] = btab[(dy * 15 + dx) * NHEADS + head];
            }
        }
    }
}

// ---------------- halo fill for XP: wp 0..3, 256..263 ------------------------
__global__ __launch_bounds__(256) void halo_kernel(u16* __restrict__ xp)
{
    int i = blockIdx.x * 256 + threadIdx.x;
    if (i >= 129024 * 12) return;
    int row = i / 12, c = i % 12;
    int wp = (c < 4) ? c : 252 + c;
    u16 v = 0;
    if (wp == 256) v = xp[row * XP_W + 254];
    xp[row * XP_W + wp] = v;
}

// ---------------- Kernel B: sepconv bf16 MFMA, K=4096, pipelined -------------
// grid 504 = (b,h), XCD-swizzled. 512 thr, 8 waves of 128co x 64w.
__global__ __launch_bounds__(512, 2) void sepconv_mfma(
    const u16* __restrict__ xp, const u16* __restrict__ WT,
    const u16* __restrict__ ZP,
    const float* __restrict__ b_h, const float* __restrict__ b_v,
    float* __restrict__ P)
{
    __shared__ u16 As[2][8192];       // [kb][co^swz][8]
    __shared__ u16 Bs[2][256 * 36];   // [w][kk], rows padded to 36 u16

    const int bid = blockIdx.x;                   // 504 = 8*63, bijective swizzle
    const int zz = (bid & 7) * 63 + (bid >> 3);
    const int h = zz % HC, b = zz / HC;
    const int tid = threadIdx.x;
    const int lane = tid & 63, wid = tid >> 6;
    const int wr = wid >> 2, wc = wid & 3;        // 2 co-halves x 4 w-quarters
    const int cq = lane & 15, kb = lane >> 4;

    const int wl2 = (tid & 127) * 2;              // w pair
    const int oc = tid >> 7;                      // k-octet 0..3

    const u16* hcur[8];
    int hstep[8];
    #pragma unroll
    for (int t = 0; t < 8; ++t) {
        int j = h + t - 3;
        bool valid = (j >= 0 && j <= 252);
        int jr = (j == 252) ? 250 : j;
        hcur[t] = valid ? (xp + (size_t)b * XP_CHW + (size_t)jr * XP_W) : ZP;
        hstep[t] = valid ? 4 * XP_HW : 0;
    }
    const u16* vbase = xp + (size_t)b * XP_CHW + (size_t)h * XP_W;
    const int hvoff = oc * XP_HW + wl2 + 4;

    const int bw0 = wl2 * 36 + oc * 8;
    const int bw1 = bw0 + 36;

    f32x4 acc[8][4];
    #pragma unroll
    for (int m = 0; m < 8; ++m)
        #pragma unroll
        for (int n = 0; n < 4; ++n) acc[m][n] = (f32x4){0.f, 0.f, 0.f, 0.f};

    u32x4 rA[2];
    u32 rB[8];

    // A LDS chunk swizzle: chunk = blk*256 + (idx ^ (blk<<1))
    int aw0, aw1;
    {
        int c0 = tid, c1 = 512 + tid;
        aw0 = ((c0 >> 8) * 256 + ((c0 & 255) ^ (((c0 >> 8) & 3) << 1))) * 8;
        aw1 = ((c1 >> 8) * 256 + ((c1 & 255) ^ (((c1 >> 8) & 3) << 1))) * 8;
    }

    // ---- prologue: load + write step 0 ----
    rA[0] = *(const u32x4*)(WT + (size_t)tid * 8);
    rA[1] = *(const u32x4*)(WT + (size_t)(512 + tid) * 8);
    #pragma unroll
    for (int t = 0; t < 8; ++t)
        rB[t] = *(const u32*)(hcur[t] + hvoff);
    *(u32x4*)&As[0][aw0] = rA[0];
    *(u32x4*)&As[0][aw1] = rA[1];
    {
        union { bf16x8 v; u32 u[4]; } p0, p1;
        #pragma unroll
        for (int q = 0; q < 4; ++q) {
            p0.u[q] = __builtin_amdgcn_perm(rB[2 * q + 1], rB[2 * q], 0x05040100u);
            p1.u[q] = __builtin_amdgcn_perm(rB[2 * q + 1], rB[2 * q], 0x07060302u);
        }
        *(bf16x8*)&Bs[0][bw0] = p0.v;
        *(bf16x8*)&Bs[0][bw1] = p1.v;
    }

    for (int s = 0; s < 128; ++s) {
        const int cur = s & 1;
        const int s1 = s + 1;
        const bool hph1 = (s1 < 64);
        if (s1 < 128) {
            rA[0] = *(const u32x4*)(WT + (size_t)s1 * 8192 + (size_t)tid * 8);
            rA[1] = *(const u32x4*)(WT + (size_t)s1 * 8192 + (size_t)(512 + tid) * 8);
            if (hph1) {
                #pragma unroll
                for (int t = 0; t < 8; ++t) hcur[t] += hstep[t];
                #pragma unroll
                for (int t = 0; t < 8; ++t)
                    rB[t] = *(const u32*)(hcur[t] + hvoff);
            } else {
                int off = ((s1 - 64) * 4 + oc) * XP_HW + wl2;
                #pragma unroll
                for (int l = 0; l < 6; ++l)
                    rB[l] = *(const u32*)(vbase + off + 2 * l);
            }
        }
        __syncthreads();

        bf16x8 af[8], bfr[4];
        #pragma unroll
        for (int m = 0; m < 8; ++m) {
            int row = wr * 128 + m * 16 + cq;
            af[m] = *(const bf16x8*)&As[cur][(kb * 256 + (row ^ (kb << 1))) * 8];
        }
        #pragma unroll
        for (int n = 0; n < 4; ++n)
            bfr[n] = *(const bf16x8*)&Bs[cur][(wc * 64 + n * 16 + cq) * 36 + kb * 8];
        #pragma unroll
        for (int m = 0; m < 8; ++m)
            #pragma unroll
            for (int n = 0; n < 4; ++n)
                acc[m][n] = __builtin_amdgcn_mfma_f32_16x16x32_bf16(af[m], bfr[n], acc[m][n], 0, 0, 0);

        if (s1 < 128) {
            const int nxt = cur ^ 1;
            *(u32x4*)&As[nxt][aw0] = rA[0];
            *(u32x4*)&As[nxt][aw1] = rA[1];
            union { bf16x8 v; u32 u[4]; } p0, p1;
            if (hph1) {
                #pragma unroll
                for (int q = 0; q < 4; ++q) {
                    p0.u[q] = __builtin_amdgcn_perm(rB[2 * q + 1], rB[2 * q], 0x05040100u);
                    p1.u[q] = __builtin_amdgcn_perm(rB[2 * q + 1], rB[2 * q], 0x07060302u);
                }
            } else {
                #pragma unroll
                for (int q = 0; q < 4; ++q)
                    p0.u[q] = __builtin_amdgcn_alignbit(rB[q + 1], rB[q], 16);
                p1.u[0] = rB[1]; p1.u[1] = rB[2];
                p1.u[2] = rB[3]; p1.u[3] = rB[4];
            }
            *(bf16x8*)&Bs[nxt][bw0] = p0.v;
            *(bf16x8*)&Bs[nxt][bw1] = p1.v;
        }
    }

    // ---- epilogue: bias + fp32 store ----
    const int rq = lane >> 4, cc = lane & 15;
    #pragma unroll
    for (int m = 0; m < 8; ++m) {
        int cgb = wr * 128 + m * 16 + rq * 4;
        float bias[4];
        #pragma unroll
        for (int rr = 0; rr < 4; ++rr) bias[rr] = b_h[cgb + rr] + b_v[cgb + rr];
        #pragma unroll
        for (int n = 0; n < 4; ++n) {
            int wg = wc * 64 + n * 16 + cc;
            if (wg < WC) {
                #pragma unroll
                for (int rr = 0; rr < 4; ++rr)
                    P[((size_t)(b * CD + cgb + rr) * HC + h) * WC + wg] = acc[m][n][rr] + bias[rr];
            }
        }
    }
}

// ---------------- Kernel C: depthwise 8x8 conv + BN -> bf16 Y ----------------
__global__ __launch_bounds__(256) void dwbn_kernel(
    const float* __restrict__ P, const float* __restrict__ w_dw,
    const float* __restrict__ gamma, const float* __restrict__ beta,
    const float* __restrict__ mean, const float* __restrict__ var,
    __hip_bfloat16* __restrict__ Yb)
{
    __shared__ float ps[15][42];
    __shared__ float wd[64];
    const int bw = blockIdx.x, bh = blockIdx.y, bz = blockIdx.z;
    const int b = bz >> 8, c = bz & 255;
    const int h0 = bh * 8, w0 = bw * 32;
    const int tid = threadIdx.x;
    if (tid < 64) wd[tid] = w_dw[c * 64 + tid];
    for (int it = 0; it < 3; ++it) {
        int flat = tid + it * 256;
        if (flat < 630) {
            int row = flat / 42, col = flat % 42;
            int j = h0 - 3 + row, wcol = w0 - 3 + col;
            float v = 0.f;
            if (j >= 0 && j <= HC && wcol >= 0 && wcol <= WC) {
                int jr = (j == HC) ? (HC - 2) : j;
                int wr2 = (wcol == WC) ? (WC - 2) : wcol;
                v = P[((b * CD + c) * HC + jr) * WC + wr2];
            }
            ps[row][col] = v;
        }
    }
    __syncthreads();
    const int r = tid >> 5, cc = tid & 31;
    const int h = h0 + r, w = w0 + cc;
    if (h < HC && w < WC) {
        float s = 0.f;
        #pragma unroll
        for (int u = 0; u < 8; ++u)
            #pragma unroll
            for (int v2 = 0; v2 < 8; ++v2)
                s += wd[u * 8 + v2] * ps[r + u][cc + v2];
        const float inv = gamma[c] * rsqrtf(var[c] + 1e-5f);
        Yb[((b * CD + c) * HC + h) * WC + w] = __float2bfloat16(s * inv + (beta[c] - mean[c] * inv));
    }
}

// ---------------- Kernel D: pointwise 1x1, bf16 MFMA, K=256, pipelined -------
// grid 504 = (b,h), XCD-swizzled. 512 thr, 8 waves of 128co x 64w.
__global__ __launch_bounds__(512, 2) void pw_mfma(
    const u16* __restrict__ Y, const u16* __restrict__ WP,
    float* __restrict__ O)
{
    __shared__ u16 As[2][8192];
    __shared__ u16 Bs[2][256 * 36];

    const int bid = blockIdx.x;
    const int zz = (bid & 7) * 63 + (bid >> 3);
    const int h = zz % HC, b = zz / HC;
    const int tid = threadIdx.x;
    const int lane = tid & 63, wid = tid >> 6;
    const int wr = wid >> 2, wc = wid & 3;
    const int cq = lane & 15, kb = lane >> 4;

    const int wl2 = (tid & 127) * 2;
    const int oc = tid >> 7;

    const u16* yb = Y + ((size_t)(b * 256 + oc * 8) * HC + h) * WC + wl2;

    const int bw0 = wl2 * 36 + oc * 8;
    const int bw1 = bw0 + 36;

    f32x4 acc[8][4];
    #pragma unroll
    for (int m = 0; m < 8; ++m)
        #pragma unroll
        for (int n = 0; n < 4; ++n) acc[m][n] = (f32x4){0.f, 0.f, 0.f, 0.f};

    u32x4 rA[2];
    u32 rB[8];

    int aw0, aw1;
    {
        int c0 = tid, c1 = 512 + tid;
        aw0 = ((c0 >> 8) * 256 + ((c0 & 255) ^ (((c0 >> 8) & 3) << 1))) * 8;
        aw1 = ((c1 >> 8) * 256 + ((c1 & 255) ^ (((c1 >> 8) & 3) << 1))) * 8;
    }

    rA[0] = *(const u32x4*)(WP + (size_t)tid * 8);
    rA[1] = *(const u32x4*)(WP + (size_t)(512 + tid) * 8);
    #pragma unroll
    for (int j = 0; j < 8; ++j)
        rB[j] = *(const u32*)(yb + (size_t)j * (HC * WC));
    *(u32x4*)&As[0][aw0] = rA[0];
    *(u32x4*)&As[0][aw1] = rA[1];
    {
        union { bf16x8 v; u32 u[4]; } p0, p1;
        #pragma unroll
        for (int q = 0; q < 4; ++q) {
            p0.u[q] = __builtin_amdgcn_perm(rB[2 * q + 1], rB[2 * q], 0x05040100u);
            p1.u[q] = __builtin_amdgcn_perm(rB[2 * q + 1], rB[2 * q], 0x07060302u);
        }
        *(bf16x8*)&Bs[0][bw0] = p0.v;
        *(bf16x8*)&Bs[0][bw1] = p1.v;
    }

    for (int s = 0; s < 8; ++s) {
        const int cur = s & 1;
        const int s1 = s + 1;
        if (s1 < 8) {
            rA[0] = *(const u32x4*)(WP + (size_t)s1 * 8192 + (size_t)tid * 8);
            rA[1] = *(const u32x4*)(WP + (size_t)s1 * 8192 + (size_t)(512 + tid) * 8);
            #pragma unroll
            for (int j = 0; j < 8; ++j)
                rB[j] = *(const u32*)(yb + (size_t)(s1 * 32 + j) * (HC * WC));
        }
        __syncthreads();

        bf16x8 af[8], bfr[4];
        #pragma unroll
        for (int m = 0; m < 8; ++m) {
            int row = wr * 128 + m * 16 + cq;
            af[m] = *(const bf16x8*)&As[cur][(kb * 256 + (row ^ (kb << 1))) * 8];
        }
        #pragma unroll
        for (int n = 0; n < 4; ++n)
            bfr[n] = *(const bf16x8*)&Bs[cur][(wc * 64 + n * 16 + cq) * 36 + kb * 8];
        #pragma unroll
        for (int m = 0; m < 8; ++m)
            #pragma unroll
            for (int n = 0; n < 4; ++n)
                acc[m][n] = __builtin_amdgcn_mfma_f32_16x16x32_bf16(af[m], bfr[n], acc[m][n], 0, 0, 0);

        if (s1 < 8) {
            const int nxt = cur ^ 1;
            *(u32x4*)&As[nxt][aw0] = rA[0];
            *(u32x4*)&As[nxt][aw1] = rA[1];
            union { bf16x8 v; u32 u[4]; } p0, p1;
            #pragma unroll
            for (int q = 0; q < 4; ++q) {
                p0.u[q] = __builtin_amdgcn_perm(rB[2 * q + 1], rB[2 * q], 0x05040100u);
                p1.u[q] = __builtin_amdgcn_perm(rB[2 * q + 1], rB[2 * q], 0x07060302u);
            }
            *(bf16x8*)&Bs[nxt][bw0] = p0.v;
            *(bf16x8*)&Bs[nxt][bw1] = p1.v;
        }
    }

    const int rq = lane >> 4, cc = lane & 15;
    #pragma unroll
    for (int m = 0; m < 8; ++m) {
        int cgb = wr * 128 + m * 16 + rq * 4;
        #pragma unroll
        for (int n = 0; n < 4; ++n) {
            int wg = wc * 64 + n * 16 + cc;
            if (wg < WC) {
                #pragma unroll
                for (int rr = 0; rr < 4; ++rr)
                    O[((size_t)(b * CD + cgb + rr) * HC + h) * WC + wg] = acc[m][n][rr];
            }
        }
    }
}

extern "C" void kernel_launch(void* const* d_in, const int* in_sizes, int n_in,
                              void* d_out, int out_size, void* d_ws, size_t ws_size,
                              hipStream_t stream)
{
    const float* x      = (const float*)d_in[0];
    const float* w_qkv  = (const float*)d_in[1];
    const float* bias_t = (const float*)d_in[2];
    const float* w_h    = (const float*)d_in[3];
    const float* b_h    = (const float*)d_in[4];
    const float* w_v    = (const float*)d_in[5];
    const float* b_v    = (const float*)d_in[6];
    const float* w_dw   = (const float*)d_in[7];
    const float* bn_g   = (const float*)d_in[8];
    const float* bn_b   = (const float*)d_in[9];
    const float* bn_m   = (const float*)d_in[10];
    const float* bn_v   = (const float*)d_in[11];
    const float* w_pw   = (const float*)d_in[12];
    float* out = (float*)d_out;

    u16* wsu = (u16*)d_ws;
    const u16* XPu = wsu;
    const u16* ZPu = wsu + ZP_OFF / 2;
    const u16* WTu = wsu + WT_OFF / 2;
    const u16* WPu = wsu + WPW_OFF / 2;
    const u16* WQu = wsu + WQ_OFF / 2;
    const float* BFu = (const float*)(wsu + BIAS_OFF / 2);

    // wprep -> attn(MFMA) -> halo -> sepconv(MFMA) -> dwbn -> pw(MFMA)
    wprep_kernel<<<5984, 256, 0, stream>>>(w_h, w_v, w_pw, w_qkv, bias_t, wsu);
    attn_mfma<<<2048, 512, 0, stream>>>(x, WQu, BFu, wsu);
    halo_kernel<<<6048, 256, 0, stream>>>(wsu);
    sepconv_mfma<<<504, 512, 0, stream>>>(XPu, WTu, ZPu, b_h, b_v, out);
    dwbn_kernel<<<dim3(8, 32, 512), 256, 0, stream>>>(out, w_dw, bn_g, bn_b, bn_m, bn_v,
                                                      (__hip_bfloat16*)d_ws);
    pw_mfma<<<504, 512, 0, stream>>>(wsu, WPu, out);
}

// Round 6
// 677.124 us; speedup vs baseline: 9.6630x; 1.1370x over previous
//
#include <hip/hip_runtime.h>
#include <hip/hip_bf16.h>

#define HC 252
#define WC 252
#define CD 256
#define NHEADS 16

// XP padded image: [b][ci][h 0..251][wp 0..263], wp = w_img + 4
#define XP_W 264
#define XP_HW (252*264)
#define XP_CHW (256*252*264)

typedef unsigned short u16;
typedef unsigned int u32;
typedef __attribute__((ext_vector_type(8))) short bf16x8;
typedef __attribute__((ext_vector_type(4))) float f32x4;
typedef __attribute__((ext_vector_type(4))) u32 u32x4;
typedef __attribute__((ext_vector_type(2))) u32 u32x2;

// ---- workspace layout (bytes) ----
#define XP_BYTES (2u * (unsigned)XP_CHW * 2u)      // 68,124,672
#define ZP_OFF   XP_BYTES
#define ZP_BYTES 409600u
#define WT_OFF   (ZP_OFF + ZP_BYTES)
#define WT_ELEMS (128*8192)                        // 1,048,576 bf16 [s][kb][co][8]
#define WPW_OFF  (WT_OFF + (unsigned)WT_ELEMS*2u)
#define WPW_ELEMS (8*8192)                         // 65,536 bf16
#define WQ_OFF   (WPW_OFF + (unsigned)WPW_ELEMS*2u)
#define WQ_ELEMS (768*256)                         // 196,608 bf16
#define BIAS_OFF (WQ_OFF + (unsigned)WQ_ELEMS*2u)

__device__ __forceinline__ u16 bfu(float f) {
    __hip_bfloat16 h = __float2bfloat16(f);
    return *(reinterpret_cast<u16*>(&h));
}
__device__ __forceinline__ u32 pack2(float a, float b) {
    return (u32)bfu(a) | ((u32)bfu(b) << 16);
}

// ---------------- Kernel A: fused qkv + window attention (MFMA) --------------
// grid 2048 (XCD-swizzled), 256 threads (4 waves, 4 heads/wave, sequential).
// LDS 72KB -> 2 blocks/CU for cross-block MFMA/VALU/stage overlap.
__global__ __launch_bounds__(256, 2) void attn_mfma(
    const float* __restrict__ x, const u16* __restrict__ WQ,
    const float* __restrict__ BIASF, u16* __restrict__ xp)
{
    // [0,32768): Xwin[pos][ci] bf16, swz byte = pos*512 + ((ci*2)^((pos&7)<<4))
    // per wave (10240B @ 32768+wid*10240): Q[2048] K[2048] V[2048] P[4096]
    __shared__ __align__(16) char smem[73728];

    const int bid = blockIdx.x;
    const int zz = (bid & 7) * 256 + (bid >> 3);   // XCD-bijective swizzle
    const int wx = zz & 31, wy = (zz >> 5) & 31, b = zz >> 10;
    const int tid = threadIdx.x;
    const int lane = tid & 63, wid = tid >> 6;
    const int g = lane >> 4, li = lane & 15;

    // ---- stage Xwin (fp32 x -> bf16 LDS, transposed, reflect-padded) ----
    {
        int ci = tid;
        const float* srcc = x + (size_t)(b * 256 + ci) * (HC * WC);
        #pragma unroll
        for (int r = 0; r < 8; ++r) {
            int h = wy * 8 + r; if (h >= HC) h = 2 * HC - 2 - h;
            const float* src = srcc + h * WC;
            float v[8];
            if (wx == 31) {
                #pragma unroll
                for (int c = 0; c < 8; ++c) {
                    int w = 248 + c; if (w >= WC) w = 2 * WC - 2 - w;
                    v[c] = src[w];
                }
            } else {
                float4 f0 = *(const float4*)(src + wx * 8);
                float4 f1 = *(const float4*)(src + wx * 8 + 4);
                v[0]=f0.x; v[1]=f0.y; v[2]=f0.z; v[3]=f0.w;
                v[4]=f1.x; v[5]=f1.y; v[6]=f1.z; v[7]=f1.w;
            }
            #pragma unroll
            for (int c = 0; c < 8; ++c) {
                int pos = r * 8 + c;
                int byte = pos * 512 + ((ci * 2) ^ ((pos & 7) << 4));
                *(u16*)(smem + byte) = bfu(v[c]);
            }
        }
    }
    __syncthreads();

    const int WB = 32768 + wid * 10240;
    char* Qb = smem + WB;
    char* Kb = smem + WB + 2048;
    char* Vb = smem + WB + 4096;
    char* Pb = smem + WB + 6144;

    const bf16x8 zf = {0,0,0,0,0,0,0,0};

    #pragma unroll 1
    for (int hh = 0; hh < 4; ++hh) {
        const int head = wid * 4 + hh;

        // ---- qkv for this head: rows head*16.. of q/k/v parts ----
        f32x4 acc[3][4];
        #pragma unroll
        for (int p = 0; p < 3; ++p)
            #pragma unroll
            for (int nf = 0; nf < 4; ++nf) acc[p][nf] = (f32x4){0.f,0.f,0.f,0.f};

        for (int ks = 0; ks < 8; ++ks) {
            bf16x8 bx[4];
            #pragma unroll
            for (int nf = 0; nf < 4; ++nf) {
                int pos = 16 * nf + li;
                int byte = pos * 512 + ((ks * 64 + 16 * g) ^ ((pos & 7) << 4));
                bx[nf] = *(const bf16x8*)(smem + byte);
            }
            bf16x8 aw[3];
            #pragma unroll
            for (int p = 0; p < 3; ++p) {
                int o = p * 256 + head * 16 + li;
                aw[p] = *(const bf16x8*)(WQ + o * 256 + ks * 32 + 8 * g);
            }
            __builtin_amdgcn_s_setprio(1);
            #pragma unroll
            for (int p = 0; p < 3; ++p)
                #pragma unroll
                for (int nf = 0; nf < 4; ++nf)
                    acc[p][nf] = __builtin_amdgcn_mfma_f32_16x16x32_bf16(aw[p], bx[nf], acc[p][nf], 0, 0, 0);
            __builtin_amdgcn_s_setprio(0);
        }

        // ---- epilogue: Q/K -> [pos][d] (swz), V -> [q][d][8pos] ----
        #pragma unroll
        for (int p = 0; p < 3; ++p) {
            if (p < 2) {
                char* base = (p == 0) ? Qb : Kb;
                #pragma unroll
                for (int nf = 0; nf < 4; ++nf) {
                    int pos = 16 * nf + li;
                    u32 lo = pack2(acc[p][nf][0], acc[p][nf][1]);
                    u32 hi = pack2(acc[p][nf][2], acc[p][nf][3]);
                    int byte = pos * 32 + ((8 * g) ^ (((pos >> 2) & 1) << 4));
                    *(u32x2*)(base + byte) = (u32x2){lo, hi};
                }
            } else {
                #pragma unroll
                for (int nf = 0; nf < 4; ++nf) {
                    int pos = 16 * nf + li;
                    #pragma unroll
                    for (int r = 0; r < 4; ++r) {
                        int d = 4 * g + r;
                        int byte = (pos >> 3) * 256 + d * 16 + (pos & 7) * 2;
                        *(u16*)(Vb + byte) = bfu(acc[p][nf][r]);
                    }
                }
            }
        }

        // ---- QK^T (k=0..15 real, 16..31 zero) ----
        f32x4 s[4][4];
        #pragma unroll
        for (int mf = 0; mf < 4; ++mf)
            #pragma unroll
            for (int nf = 0; nf < 4; ++nf) s[mf][nf] = (f32x4){0.f,0.f,0.f,0.f};
        bf16x8 bk[4];
        #pragma unroll
        for (int nf = 0; nf < 4; ++nf) {
            int pos = 16 * nf + li;
            bk[nf] = (g < 2) ? *(const bf16x8*)(Kb + pos * 32 + ((16 * g) ^ (((pos >> 2) & 1) << 4))) : zf;
        }
        __builtin_amdgcn_s_setprio(1);
        #pragma unroll
        for (int mf = 0; mf < 4; ++mf) {
            int pos = 16 * mf + li;
            bf16x8 aq = (g < 2) ? *(const bf16x8*)(Qb + pos * 32 + ((16 * g) ^ (((pos >> 2) & 1) << 4))) : zf;
            #pragma unroll
            for (int nf = 0; nf < 4; ++nf)
                s[mf][nf] = __builtin_amdgcn_mfma_f32_16x16x32_bf16(aq, bk[nf], s[mf][nf], 0, 0, 0);
        }
        __builtin_amdgcn_s_setprio(0);

        // ---- bias + exp + row sums (no max-sub: scores bounded small) ----
        f32x4 e[4][4];
        f32x4 rs[4];
        #pragma unroll
        for (int mf = 0; mf < 4; ++mf) rs[mf] = (f32x4){0.f,0.f,0.f,0.f};
        #pragma unroll
        for (int mf = 0; mf < 4; ++mf)
            #pragma unroll
            for (int nf = 0; nf < 4; ++nf) {
                f32x4 b4 = *(const f32x4*)(BIASF + (((head * 4 + mf) * 4 + nf) * 64 + lane) * 4);
                #pragma unroll
                for (int r = 0; r < 4; ++r) {
                    float ev = __expf(s[mf][nf][r] * 0.25f + b4[r]);
                    e[mf][nf][r] = ev;
                    rs[mf][r] += ev;
                }
            }
        #pragma unroll
        for (int mf = 0; mf < 4; ++mf)
            #pragma unroll
            for (int r = 0; r < 4; ++r) {
                float t = rs[mf][r];
                t += __shfl_xor(t, 1); t += __shfl_xor(t, 2);
                t += __shfl_xor(t, 4); t += __shfl_xor(t, 8);
                rs[mf][r] = t;
            }

        // ---- PV in two j-halves through the 4KB P buffer ----
        f32x4 o[4];
        #pragma unroll
        for (int mf = 0; mf < 4; ++mf) o[mf] = (f32x4){0.f,0.f,0.f,0.f};
        const bool even = !(lane & 1);
        #pragma unroll
        for (int hf = 0; hf < 2; ++hf) {
            #pragma unroll
            for (int mf = 0; mf < 4; ++mf)
                #pragma unroll
                for (int nfl = 0; nfl < 2; ++nfl) {
                    f32x4 ee = e[mf][2 * hf + nfl];
                    float p0 = __shfl_xor(ee[0], 1), p1 = __shfl_xor(ee[1], 1);
                    float p2 = __shfl_xor(ee[2], 1), p3 = __shfl_xor(ee[3], 1);
                    int jl = 16 * nfl + (li & ~1);
                    u32 w0, w1; int r0;
                    if (even) { w0 = pack2(ee[0], p0); w1 = pack2(ee[1], p1); r0 = 0; }
                    else      { w0 = pack2(p2, ee[2]); w1 = pack2(p3, ee[3]); r0 = 2; }
                    int i0 = 16 * mf + 4 * g + r0, i1 = i0 + 1;
                    *(u32*)(Pb + i0 * 64 + ((2 * jl) ^ ((i0 & 3) << 4))) = w0;
                    *(u32*)(Pb + i1 * 64 + ((2 * jl) ^ ((i1 & 3) << 4))) = w1;
                }
            bf16x8 bv = *(const bf16x8*)(Vb + (4 * hf + g) * 256 + li * 16);
            __builtin_amdgcn_s_setprio(1);
            #pragma unroll
            for (int mf = 0; mf < 4; ++mf) {
                int i = 16 * mf + li;
                bf16x8 ap = *(const bf16x8*)(Pb + i * 64 + ((16 * g) ^ ((i & 3) << 4)));
                o[mf] = __builtin_amdgcn_mfma_f32_16x16x32_bf16(ap, bv, o[mf], 0, 0, 0);
            }
            __builtin_amdgcn_s_setprio(0);
        }

        // ---- scale by 1/rowsum and store 4 bf16 (8B) into XP interior ----
        #pragma unroll
        for (int mf = 0; mf < 4; ++mf) {
            int h = wy * 8 + 2 * mf + (g >> 1);
            int wbase = wx * 8 + 4 * (g & 1);
            if (h < HC && wbase < WC) {
                float v0 = o[mf][0] / rs[mf][0], v1 = o[mf][1] / rs[mf][1];
                float v2 = o[mf][2] / rs[mf][2], v3 = o[mf][3] / rs[mf][3];
                size_t idx = ((size_t)(b * 256 + head * 16 + li) * HC + h) * XP_W + wbase + 4;
                *(u32x2*)(xp + idx) = (u32x2){pack2(v0, v1), pack2(v2, v3)};
            }
        }
    }
}

// ---------------- weight prep: WT2, WP2, ZP, WQ(bf16), BIASF -----------------
__global__ __launch_bounds__(256) void wprep_kernel(
    const float* __restrict__ wh, const float* __restrict__ wv,
    const float* __restrict__ wpw, const float* __restrict__ wqkv,
    const float* __restrict__ btab, u16* __restrict__ wsu)
{
    int i = blockIdx.x * 256 + threadIdx.x;
    u16* WT = wsu + WT_OFF / 2;
    u16* WP = wsu + WPW_OFF / 2;
    u16* ZP = wsu + ZP_OFF / 2;
    u16* WQp = wsu + WQ_OFF / 2;
    float* BF = (float*)(wsu + BIAS_OFF / 2);
    if (i < WT_ELEMS) {
        // WT2[s][kb][co][8]: k = s*32 + kb*8 + j
        int j = i & 7, co = (i >> 3) & 255, kb = (i >> 11) & 3, s = i >> 13;
        float v = (s < 64) ? wh[co * 2048 + s * 32 + kb * 8 + j]
                           : wv[co * 2048 + (s - 64) * 32 + kb * 8 + j];
        WT[i] = bfu(v);
    } else if (i < WT_ELEMS + WPW_ELEMS) {
        int i2 = i - WT_ELEMS;
        int j = i2 & 7, co = (i2 >> 3) & 255, kb = (i2 >> 11) & 3, s = i2 >> 13;
        WP[i2] = bfu(wpw[co * 256 + s * 32 + kb * 8 + j]);
    } else if (i < WT_ELEMS + WPW_ELEMS + (int)(ZP_BYTES / 2)) {
        ZP[i - WT_ELEMS - WPW_ELEMS] = 0;
    } else if (i < WT_ELEMS + WPW_ELEMS + (int)(ZP_BYTES / 2) + WQ_ELEMS) {
        int i4 = i - WT_ELEMS - WPW_ELEMS - (int)(ZP_BYTES / 2);
        WQp[i4] = bfu(wqkv[i4]);
    } else {
        int i5 = i - WT_ELEMS - WPW_ELEMS - (int)(ZP_BYTES / 2) - WQ_ELEMS;
        if (i5 < 16384) {
            int lane = i5 & 63, nf = (i5 >> 6) & 3, mf = (i5 >> 8) & 3, head = i5 >> 10;
            int gg = lane >> 4, ll = lane & 15;
            #pragma unroll
            for (int r = 0; r < 4; ++r) {
                int row = 16 * mf + 4 * gg + r;
                int col = 16 * nf + ll;
                int dy = (row >> 3) - (col >> 3) + 7;
                int dx = (row & 7) - (col & 7) + 7;
                BF[i5 * 4 + r] = btab[(dy * 15 + dx) * NHEADS + head];
            }
        }
    }
}

// ---------------- halo fill for XP: wp 0..3, 256..263 ------------------------
__global__ __launch_bounds__(256) void halo_kernel(u16* __restrict__ xp)
{
    int i = blockIdx.x * 256 + threadIdx.x;
    if (i >= 129024 * 12) return;
    int row = i / 12, c = i % 12;
    int wp = (c < 4) ? c : 252 + c;
    u16 v = 0;
    if (wp == 256) v = xp[row * XP_W + 254];
    xp[row * XP_W + wp] = v;
}

// ---------------- Kernel B: sepconv bf16 MFMA, K=4096, pipelined -------------
// grid 504 = (b,h), XCD-swizzled. 512 thr, 8 waves of 128co x 64w.
__global__ __launch_bounds__(512, 2) void sepconv_mfma(
    const u16* __restrict__ xp, const u16* __restrict__ WT,
    const u16* __restrict__ ZP,
    const float* __restrict__ b_h, const float* __restrict__ b_v,
    float* __restrict__ P)
{
    __shared__ u16 As[2][8192];       // [kb][co^swz][8]
    __shared__ u16 Bs[2][256 * 36];   // [w][kk], rows padded to 36 u16

    const int bid = blockIdx.x;                   // 504 = 8*63, bijective swizzle
    const int zz = (bid & 7) * 63 + (bid >> 3);
    const int h = zz % HC, b = zz / HC;
    const int tid = threadIdx.x;
    const int lane = tid & 63, wid = tid >> 6;
    const int wr = wid >> 2, wc = wid & 3;        // 2 co-halves x 4 w-quarters
    const int cq = lane & 15, kb = lane >> 4;

    const int wl2 = (tid & 127) * 2;              // w pair
    const int oc = tid >> 7;                      // k-octet 0..3

    const u16* hcur[8];
    int hstep[8];
    #pragma unroll
    for (int t = 0; t < 8; ++t) {
        int j = h + t - 3;
        bool valid = (j >= 0 && j <= 252);
        int jr = (j == 252) ? 250 : j;
        hcur[t] = valid ? (xp + (size_t)b * XP_CHW + (size_t)jr * XP_W) : ZP;
        hstep[t] = valid ? 4 * XP_HW : 0;
    }
    const u16* vbase = xp + (size_t)b * XP_CHW + (size_t)h * XP_W;
    const int hvoff = oc * XP_HW + wl2 + 4;

    const int bw0 = wl2 * 36 + oc * 8;
    const int bw1 = bw0 + 36;

    f32x4 acc[8][4];
    #pragma unroll
    for (int m = 0; m < 8; ++m)
        #pragma unroll
        for (int n = 0; n < 4; ++n) acc[m][n] = (f32x4){0.f, 0.f, 0.f, 0.f};

    u32x4 rA[2];
    u32 rB[8];

    // A LDS chunk swizzle: chunk = blk*256 + (idx ^ (blk<<1))
    int aw0, aw1;
    {
        int c0 = tid, c1 = 512 + tid;
        aw0 = ((c0 >> 8) * 256 + ((c0 & 255) ^ (((c0 >> 8) & 3) << 1))) * 8;
        aw1 = ((c1 >> 8) * 256 + ((c1 & 255) ^ (((c1 >> 8) & 3) << 1))) * 8;
    }

    // ---- prologue: load + write step 0 ----
    rA[0] = *(const u32x4*)(WT + (size_t)tid * 8);
    rA[1] = *(const u32x4*)(WT + (size_t)(512 + tid) * 8);
    #pragma unroll
    for (int t = 0; t < 8; ++t)
        rB[t] = *(const u32*)(hcur[t] + hvoff);
    *(u32x4*)&As[0][aw0] = rA[0];
    *(u32x4*)&As[0][aw1] = rA[1];
    {
        union { bf16x8 v; u32 u[4]; } p0, p1;
        #pragma unroll
        for (int q = 0; q < 4; ++q) {
            p0.u[q] = __builtin_amdgcn_perm(rB[2 * q + 1], rB[2 * q], 0x05040100u);
            p1.u[q] = __builtin_amdgcn_perm(rB[2 * q + 1], rB[2 * q], 0x07060302u);
        }
        *(bf16x8*)&Bs[0][bw0] = p0.v;
        *(bf16x8*)&Bs[0][bw1] = p1.v;
    }

    for (int s = 0; s < 128; ++s) {
        const int cur = s & 1;
        const int s1 = s + 1;
        const bool hph1 = (s1 < 64);
        if (s1 < 128) {
            rA[0] = *(const u32x4*)(WT + (size_t)s1 * 8192 + (size_t)tid * 8);
            rA[1] = *(const u32x4*)(WT + (size_t)s1 * 8192 + (size_t)(512 + tid) * 8);
            if (hph1) {
                #pragma unroll
                for (int t = 0; t < 8; ++t) hcur[t] += hstep[t];
                #pragma unroll
                for (int t = 0; t < 8; ++t)
                    rB[t] = *(const u32*)(hcur[t] + hvoff);
            } else {
                int off = ((s1 - 64) * 4 + oc) * XP_HW + wl2;
                #pragma unroll
                for (int l = 0; l < 6; ++l)
                    rB[l] = *(const u32*)(vbase + off + 2 * l);
            }
        }
        __syncthreads();

        bf16x8 af[8], bfr[4];
        #pragma unroll
        for (int m = 0; m < 8; ++m) {
            int row = wr * 128 + m * 16 + cq;
            af[m] = *(const bf16x8*)&As[cur][(kb * 256 + (row ^ (kb << 1))) * 8];
        }
        #pragma unroll
        for (int n = 0; n < 4; ++n)
            bfr[n] = *(const bf16x8*)&Bs[cur][(wc * 64 + n * 16 + cq) * 36 + kb * 8];
        #pragma unroll
        for (int m = 0; m < 8; ++m)
            #pragma unroll
            for (int n = 0; n < 4; ++n)
                acc[m][n] = __builtin_amdgcn_mfma_f32_16x16x32_bf16(af[m], bfr[n], acc[m][n], 0, 0, 0);

        if (s1 < 128) {
            const int nxt = cur ^ 1;
            *(u32x4*)&As[nxt][aw0] = rA[0];
            *(u32x4*)&As[nxt][aw1] = rA[1];
            union { bf16x8 v; u32 u[4]; } p0, p1;
            if (hph1) {
                #pragma unroll
                for (int q = 0; q < 4; ++q) {
                    p0.u[q] = __builtin_amdgcn_perm(rB[2 * q + 1], rB[2 * q], 0x05040100u);
                    p1.u[q] = __builtin_amdgcn_perm(rB[2 * q + 1], rB[2 * q], 0x07060302u);
                }
            } else {
                #pragma unroll
                for (int q = 0; q < 4; ++q)
                    p0.u[q] = __builtin_amdgcn_alignbit(rB[q + 1], rB[q], 16);
                p1.u[0] = rB[1]; p1.u[1] = rB[2];
                p1.u[2] = rB[3]; p1.u[3] = rB[4];
            }
            *(bf16x8*)&Bs[nxt][bw0] = p0.v;
            *(bf16x8*)&Bs[nxt][bw1] = p1.v;
        }
    }

    // ---- epilogue: bias + fp32 store ----
    const int rq = lane >> 4, cc = lane & 15;
    #pragma unroll
    for (int m = 0; m < 8; ++m) {
        int cgb = wr * 128 + m * 16 + rq * 4;
        float bias[4];
        #pragma unroll
        for (int rr = 0; rr < 4; ++rr) bias[rr] = b_h[cgb + rr] + b_v[cgb + rr];
        #pragma unroll
        for (int n = 0; n < 4; ++n) {
            int wg = wc * 64 + n * 16 + cc;
            if (wg < WC) {
                #pragma unroll
                for (int rr = 0; rr < 4; ++rr)
                    P[((size_t)(b * CD + cgb + rr) * HC + h) * WC + wg] = acc[m][n][rr] + bias[rr];
            }
        }
    }
}

// ---------------- Kernel C: depthwise 8x8 conv + BN -> bf16 Y ----------------
__global__ __launch_bounds__(256) void dwbn_kernel(
    const float* __restrict__ P, const float* __restrict__ w_dw,
    const float* __restrict__ gamma, const float* __restrict__ beta,
    const float* __restrict__ mean, const float* __restrict__ var,
    __hip_bfloat16* __restrict__ Yb)
{
    __shared__ float ps[15][42];
    __shared__ float wd[64];
    const int bw = blockIdx.x, bh = blockIdx.y, bz = blockIdx.z;
    const int b = bz >> 8, c = bz & 255;
    const int h0 = bh * 8, w0 = bw * 32;
    const int tid = threadIdx.x;
    if (tid < 64) wd[tid] = w_dw[c * 64 + tid];
    for (int it = 0; it < 3; ++it) {
        int flat = tid + it * 256;
        if (flat < 630) {
            int row = flat / 42, col = flat % 42;
            int j = h0 - 3 + row, wcol = w0 - 3 + col;
            float v = 0.f;
            if (j >= 0 && j <= HC && wcol >= 0 && wcol <= WC) {
                int jr = (j == HC) ? (HC - 2) : j;
                int wr2 = (wcol == WC) ? (WC - 2) : wcol;
                v = P[((b * CD + c) * HC + jr) * WC + wr2];
            }
            ps[row][col] = v;
        }
    }
    __syncthreads();
    const int r = tid >> 5, cc = tid & 31;
    const int h = h0 + r, w = w0 + cc;
    if (h < HC && w < WC) {
        float s = 0.f;
        #pragma unroll
        for (int u = 0; u < 8; ++u)
            #pragma unroll
            for (int v2 = 0; v2 < 8; ++v2)
                s += wd[u * 8 + v2] * ps[r + u][cc + v2];
        const float inv = gamma[c] * rsqrtf(var[c] + 1e-5f);
        Yb[((b * CD + c) * HC + h) * WC + w] = __float2bfloat16(s * inv + (beta[c] - mean[c] * inv));
    }
}

// ---------------- Kernel D: pointwise 1x1, bf16 MFMA, K=256, pipelined -------
// grid 504 = (b,h), XCD-swizzled. 512 thr, 8 waves of 128co x 64w.
__global__ __launch_bounds__(512, 2) void pw_mfma(
    const u16* __restrict__ Y, const u16* __restrict__ WP,
    float* __restrict__ O)
{
    __shared__ u16 As[2][8192];
    __shared__ u16 Bs[2][256 * 36];

    const int bid = blockIdx.x;
    const int zz = (bid & 7) * 63 + (bid >> 3);
    const int h = zz % HC, b = zz / HC;
    const int tid = threadIdx.x;
    const int lane = tid & 63, wid = tid >> 6;
    const int wr = wid >> 2, wc = wid & 3;
    const int cq = lane & 15, kb = lane >> 4;

    const int wl2 = (tid & 127) * 2;
    const int oc = tid >> 7;

    const u16* yb = Y + ((size_t)(b * 256 + oc * 8) * HC + h) * WC + wl2;

    const int bw0 = wl2 * 36 + oc * 8;
    const int bw1 = bw0 + 36;

    f32x4 acc[8][4];
    #pragma unroll
    for (int m = 0; m < 8; ++m)
        #pragma unroll
        for (int n = 0; n < 4; ++n) acc[m][n] = (f32x4){0.f, 0.f, 0.f, 0.f};

    u32x4 rA[2];
    u32 rB[8];

    int aw0, aw1;
    {
        int c0 = tid, c1 = 512 + tid;
        aw0 = ((c0 >> 8) * 256 + ((c0 & 255) ^ (((c0 >> 8) & 3) << 1))) * 8;
        aw1 = ((c1 >> 8) * 256 + ((c1 & 255) ^ (((c1 >> 8) & 3) << 1))) * 8;
    }

    rA[0] = *(const u32x4*)(WP + (size_t)tid * 8);
    rA[1] = *(const u32x4*)(WP + (size_t)(512 + tid) * 8);
    #pragma unroll
    for (int j = 0; j < 8; ++j)
        rB[j] = *(const u32*)(yb + (size_t)j * (HC * WC));
    *(u32x4*)&As[0][aw0] = rA[0];
    *(u32x4*)&As[0][aw1] = rA[1];
    {
        union { bf16x8 v; u32 u[4]; } p0, p1;
        #pragma unroll
        for (int q = 0; q < 4; ++q) {
            p0.u[q] = __builtin_amdgcn_perm(rB[2 * q + 1], rB[2 * q], 0x05040100u);
            p1.u[q] = __builtin_amdgcn_perm(rB[2 * q + 1], rB[2 * q], 0x07060302u);
        }
        *(bf16x8*)&Bs[0][bw0] = p0.v;
        *(bf16x8*)&Bs[0][bw1] = p1.v;
    }

    for (int s = 0; s < 8; ++s) {
        const int cur = s & 1;
        const int s1 = s + 1;
        if (s1 < 8) {
            rA[0] = *(const u32x4*)(WP + (size_t)s1 * 8192 + (size_t)tid * 8);
            rA[1] = *(const u32x4*)(WP + (size_t)s1 * 8192 + (size_t)(512 + tid) * 8);
            #pragma unroll
            for (int j = 0; j < 8; ++j)
                rB[j] = *(const u32*)(yb + (size_t)(s1 * 32 + j) * (HC * WC));
        }
        __syncthreads();

        bf16x8 af[8], bfr[4];
        #pragma unroll
        for (int m = 0; m < 8; ++m) {
            int row = wr * 128 + m * 16 + cq;
            af[m] = *(const bf16x8*)&As[cur][(kb * 256 + (row ^ (kb << 1))) * 8];
        }
        #pragma unroll
        for (int n = 0; n < 4; ++n)
            bfr[n] = *(const bf16x8*)&Bs[cur][(wc * 64 + n * 16 + cq) * 36 + kb * 8];
        #pragma unroll
        for (int m = 0; m < 8; ++m)
            #pragma unroll
            for (int n = 0; n < 4; ++n)
                acc[m][n] = __builtin_amdgcn_mfma_f32_16x16x32_bf16(af[m], bfr[n], acc[m][n], 0, 0, 0);

        if (s1 < 8) {
            const int nxt = cur ^ 1;
            *(u32x4*)&As[nxt][aw0] = rA[0];
            *(u32x4*)&As[nxt][aw1] = rA[1];
            union { bf16x8 v; u32 u[4]; } p0, p1;
            #pragma unroll
            for (int q = 0; q < 4; ++q) {
                p0.u[q] = __builtin_amdgcn_perm(rB[2 * q + 1], rB[2 * q], 0x05040100u);
                p1.u[q] = __builtin_amdgcn_perm(rB[2 * q + 1], rB[2 * q], 0x07060302u);
            }
            *(bf16x8*)&Bs[nxt][bw0] = p0.v;
            *(bf16x8*)&Bs[nxt][bw1] = p1.v;
        }
    }

    const int rq = lane >> 4, cc = lane & 15;
    #pragma unroll
    for (int m = 0; m < 8; ++m) {
        int cgb = wr * 128 + m * 16 + rq * 4;
        #pragma unroll
        for (int n = 0; n < 4; ++n) {
            int wg = wc * 64 + n * 16 + cc;
            if (wg < WC) {
                #pragma unroll
                for (int rr = 0; rr < 4; ++rr)
                    O[((size_t)(b * CD + cgb + rr) * HC + h) * WC + wg] = acc[m][n][rr];
            }
        }
    }
}

extern "C" void kernel_launch(void* const* d_in, const int* in_sizes, int n_in,
                              void* d_out, int out_size, void* d_ws, size_t ws_size,
                              hipStream_t stream)
{
    const float* x      = (const float*)d_in[0];
    const float* w_qkv  = (const float*)d_in[1];
    const float* bias_t = (const float*)d_in[2];
    const float* w_h    = (const float*)d_in[3];
    const float* b_h    = (const float*)d_in[4];
    const float* w_v    = (const float*)d_in[5];
    const float* b_v    = (const float*)d_in[6];
    const float* w_dw   = (const float*)d_in[7];
    const float* bn_g   = (const float*)d_in[8];
    const float* bn_b   = (const float*)d_in[9];
    const float* bn_m   = (const float*)d_in[10];
    const float* bn_v   = (const float*)d_in[11];
    const float* w_pw   = (const float*)d_in[12];
    float* out = (float*)d_out;

    u16* wsu = (u16*)d_ws;
    const u16* XPu = wsu;
    const u16* ZPu = wsu + ZP_OFF / 2;
    const u16* WTu = wsu + WT_OFF / 2;
    const u16* WPu = wsu + WPW_OFF / 2;
    const u16* WQu = wsu + WQ_OFF / 2;
    const float* BFu = (const float*)(wsu + BIAS_OFF / 2);

    // wprep -> attn(MFMA) -> halo -> sepconv(MFMA) -> dwbn -> pw(MFMA)
    wprep_kernel<<<5984, 256, 0, stream>>>(w_h, w_v, w_pw, w_qkv, bias_t, wsu);
    attn_mfma<<<2048, 256, 0, stream>>>(x, WQu, BFu, wsu);
    halo_kernel<<<6048, 256, 0, stream>>>(wsu);
    sepconv_mfma<<<504, 512, 0, stream>>>(XPu, WTu, ZPu, b_h, b_v, out);
    dwbn_kernel<<<dim3(8, 32, 512), 256, 0, stream>>>(out, w_dw, bn_g, bn_b, bn_m, bn_v,
                                                      (__hip_bfloat16*)d_ws);
    pw_mfma<<<504, 512, 0, stream>>>(wsu, WPu, out);
}